// Round 11
// baseline (423477.441 us; speedup 1.0000x reference)
//
#include <hip/hip_runtime.h>
#include <hip/hip_cooperative_groups.h>
#include <math.h>

namespace cg = cooperative_groups;

#define NA      1500
#define NEDGE   48000
#define NDIM    4500
#define NB      9
#define ZCHW    576
#define YLD     1152
#define CAPSM   640
#define CAP8    1152
#define SWEEPSB 8
#define NSWLOC  8
#define TSLOTS  180
#define SORTN   8192
#define COEFLD  864
#define NOUT    4494
#define PI_D    3.14159265358979323846

// Chebyshev filter degrees
static const int H_DEG[NB] = {24, 48, 96, 160, 320, 320, 336, 336, 272};
__device__ __constant__ int d_DEG[NB] = {24, 48, 96, 160, 320, 320, 336, 336, 272};
__device__ __constant__ double d_MASS[10] = {1.008,4.003,6.941,9.012,10.811,12.011,14.007,15.999,18.998,20.18};
__device__ __constant__ double d_BLO[NB] = {31.04695, 9.84715, 6.37590, 5.08655, 4.39385, 3.86620, 3.34740, 2.87855, -1.0e9};
__device__ __constant__ double d_BHI[NB] = {1.0e9, 31.04695, 9.84715, 6.37590, 5.08655, 4.39385, 3.86620, 3.34740, 2.87855};

// ---------------- workspace layout (bytes) ----------------
constexpr size_t O_DESC = 0;
constexpr size_t O_WM   = 32768;
constexpr size_t O_MINV = O_WM + 12288;
constexpr size_t O_GER  = O_MINV + 12288;
constexpr size_t O_CH   = O_GER + 24576;
constexpr size_t O_COEF = O_CH + 256;
constexpr size_t O_DT   = O_COEF + (size_t)NB*COEFLD*8;
constexpr size_t O_PD   = O_DT + (size_t)NDIM*9*8;
constexpr size_t O_RB   = O_PD + (size_t)NB*1152*9*8;
constexpr size_t O_EVA  = O_RB + (size_t)NB*1152*9*8;
constexpr size_t O_SID  = O_EVA + (size_t)SORTN*8;
constexpr size_t O_HCOL = O_SID + (size_t)SORTN*4;
constexpr size_t O_HV64 = O_HCOL + (size_t)NA*65*4;      // f64[1500*65*9] (spmm64)
constexpr size_t O_HV32 = O_HV64 + (size_t)NA*65*9*8;    // (reserved; legacy spacing)
constexpr size_t O_Y    = O_HV32 + (size_t)NA*65*12*4;   // hosts HA/HB/HC f32 transposed H
constexpr size_t O_HA   = O_Y;                           // float4[65*1500]  h[0..3]
constexpr size_t O_HB   = O_HA + (size_t)65*NA*16;       // float4[65*1500]  h[4..7]
constexpr size_t O_HC   = O_HB + (size_t)65*NA*16;       // float [65*1500]  h[8]
constexpr size_t O_X1   = O_Y + (size_t)NDIM*YLD*4;      // ortho X (ld=YLD); HG scratch after bjac
constexpr size_t O_X2   = O_X1 + (size_t)NDIM*YLD*8;     // cheb output (ld=YLD)
constexpr size_t O_S    = O_X2 + (size_t)NDIM*YLD*8;     // S; Z chunk aliases S after NS
constexpr size_t O_P    = O_S + (size_t)CAP8*CAP8*8;     // P
constexpr size_t O_G    = O_P + (size_t)CAP8*CAP8*8;     // Heff; during NS: Ptot ping scratch
constexpr size_t GTOT   = (size_t)8*CAPSM*CAPSM + (size_t)CAP8*CAP8;
constexpr size_t O_J    = O_G + GTOT*8;                  // Heff snapshot; during NS: Ptot pong
constexpr size_t WS_NEED = O_J + GTOT*8;                 // ~213 MB

__host__ __device__ inline size_t goffd(int g){ return (g < 8) ? (size_t)g*CAPSM*CAPSM : (size_t)8*CAPSM*CAPSM; }
__host__ inline int capb(int g){ return (g < 8) ? CAPSM : CAP8; }

// ---------------- prep ----------------
__global__ void k_prep(const int* __restrict__ z, char* ws) {
  int* desc = (int*)ws;
  double* wm = (double*)(ws + O_WM);
  double* minv = (double*)(ws + O_MINV);
  __shared__ int zb[NA];
  __shared__ int cnt[NB];
  int tid = threadIdx.x;
  if (tid < NB) cnt[tid] = 0;
  __syncthreads();
  for (int a = tid; a < NA; a += blockDim.x) {
    int zz = z[a];
    int b = (zz >= 8) ? 8 : zz;
    zb[a] = b;
    atomicAdd(&cnt[b], 1);
    double m = d_MASS[zz];
    wm[a] = 1.0/sqrt(m);
    minv[a] = 1.0/m;
  }
  __syncthreads();
  if (tid == 0) {
    int off = 0;
    for (int g = 0; g < NB; ++g) {
      desc[16+g] = 3*off;
      int ng = 3*cnt[g];
      int cap = (g < 8) ? CAPSM : CAP8;
      ng = (ng > cap) ? cap : ng;
      desc[g] = ng;
      desc[32+g] = ng + (ng & 1);
      int nb = (ng + 15)/16;
      if (nb & 1) nb++;
      desc[48+g] = nb;
      off += cnt[g];
    }
    desc[16+NB] = 3*off;
  }
  __syncthreads();
  for (int a = tid; a < NA; a += blockDim.x) {
    int b = zb[a]; int r = 0;
    for (int x = 0; x < a; ++x) r += (zb[x] == b) ? 1 : 0;
    if (r < 512) desc[64 + b*512 + r] = a;
    desc[5120 + a] = (r & 0xffff) | (b << 16);   // atom -> (rank, band)
  }
}

// ---------------- build sparse mass-weighted symmetrized H ----------------
__global__ void k_buildH(const int* __restrict__ ei, const float* __restrict__ Hi,
                         const float* __restrict__ Hij, char* ws) {
  int p = blockIdx.x, t = threadIdx.x;
  const double* wm = (const double*)(ws + O_WM);
  const double* minv = (const double*)(ws + O_MINV);
  int* hcol = (int*)(ws + O_HCOL);
  double* hv = (double*)(ws + O_HV64);
  float4* HAp = (float4*)(ws + O_HA);
  float4* HBp = (float4*)(ws + O_HB);
  float*  HCp = (float*)(ws + O_HC);
  __shared__ double rowabs[3][72];
  __shared__ double dcen[3];
  double v[9];
  int q = -1;
  if (t == 0) {
    q = p;
    double mi = minv[p];
    for (int a = 0; a < 3; ++a)
      for (int b = 0; b < 3; ++b)
        v[3*a+b] = 0.5*((double)Hi[9*p+3*a+b] + (double)Hi[9*p+3*b+a])*mi;
    for (int a = 0; a < 3; ++a) dcen[a] = v[3*a+a];
  } else if (t <= 32) {
    int off = t;
    int e = 32*p + off - 1;
    q = ei[e];
    double ww = 0.5*wm[p]*wm[q];
    for (int a = 0; a < 3; ++a)
      for (int b = 0; b < 3; ++b)
        v[3*a+b] = ww*(double)Hij[9*e+3*a+b];
  } else if (t <= 64) {
    int off = t - 32;
    int qr = (p + NA - off) % NA;
    int e = 32*qr + off - 1;
    q = ei[NEDGE + e];
    double ww = 0.5*wm[p]*wm[q];
    for (int a = 0; a < 3; ++a)
      for (int b = 0; b < 3; ++b)
        v[3*a+b] = ww*(double)Hij[9*e+3*b+a];
  }
  if (t < 65) {
    hcol[p*65+t] = q;
    for (int k = 0; k < 9; ++k)
      hv[((size_t)p*65+t)*9+k] = v[k];
    HAp[(size_t)t*NA + p] = make_float4((float)v[0],(float)v[1],(float)v[2],(float)v[3]);
    HBp[(size_t)t*NA + p] = make_float4((float)v[4],(float)v[5],(float)v[6],(float)v[7]);
    HCp[(size_t)t*NA + p] = (float)v[8];
    for (int a = 0; a < 3; ++a)
      rowabs[a][t] = fabs(v[3*a]) + fabs(v[3*a+1]) + fabs(v[3*a+2]);
  }
  __syncthreads();
  if (t == 0) {
    double hi = -1e300, lo = 1e300;
    for (int a = 0; a < 3; ++a) {
      double s = 0.0;
      for (int k = 0; k < 65; ++k) s += rowabs[a][k];
      double rad = s - fabs(dcen[a]);
      hi = fmax(hi, dcen[a] + rad);
      lo = fmin(lo, dcen[a] - rad);
    }
    double* ger = (double*)(ws + O_GER);
    ger[2*p] = hi; ger[2*p+1] = lo;
  }
}

// ---------------- spectrum bounds + Jackson-Chebyshev coefficients ----------------
__global__ void k_coeff(char* ws) {
  __shared__ double shi[256], slo[256];
  int tid = threadIdx.x;
  const double* ger = (const double*)(ws + O_GER);
  double hi = -1e300, lo = 1e300;
  for (int i = tid; i < NA; i += 256) { hi = fmax(hi, ger[2*i]); lo = fmin(lo, ger[2*i+1]); }
  shi[tid] = hi; slo[tid] = lo;
  __syncthreads();
  for (int s = 128; s > 0; s >>= 1) {
    if (tid < s) { shi[tid] = fmax(shi[tid], shi[tid+s]); slo[tid] = fmin(slo[tid], slo[tid+s]); }
    __syncthreads();
  }
  double* ch = (double*)(ws + O_CH);
  if (tid == 0) {
    double c = 0.5*(shi[0]+slo[0]);
    double h = 0.5*(shi[0]-slo[0])*1.002;
    ch[0] = c; ch[1] = h;
  }
  __syncthreads();
  double c = ch[0], h = ch[1];
  double* coef = (double*)(ws + O_COEF);
  for (int g = 0; g < NB; ++g) {
    int d = d_DEG[g];
    double xlo = fmin(1.0, fmax(-1.0, (d_BLO[g]-c)/h));
    double xhi = fmin(1.0, fmax(-1.0, (d_BHI[g]-c)/h));
    double f1 = acos(xlo), f2 = acos(xhi);
    double alp = PI_D/(double)(d+1);
    double ct = cos(alp)/sin(alp);
    for (int k = tid; k <= d; k += 256) {
      double ck = (k == 0) ? (f1-f2)/PI_D : 2.0*(sin(k*f1)-sin(k*f2))/(k*PI_D);
      double jk = ((double)(d+1-k)*cos(k*alp) + sin(k*alp)*ct)/(double)(d+1);
      coef[g*COEFLD+k] = ck*jk;
    }
  }
}

// ---------------- mass-weighted dipole/polar matrix Dt[4500][9] ----------------
__global__ void k_dt(const float* __restrict__ ded, const float* __restrict__ dep, char* ws) {
  int row = blockIdx.x*256 + threadIdx.x;
  if (row >= NDIM) return;
  int p = row/3, a = row%3;
  const double* wm = (const double*)(ws + O_WM);
  double w = wm[p];
  double* dt = (double*)(ws + O_DT) + (size_t)row*9;
  for (int cI = 0; cI < 3; ++cI) dt[cI] = w*(double)ded[9*p+3*a+cI];
  for (int cI = 0; cI < 6; ++cI) dt[3+cI] = w*(double)dep[18*p+6*a+cI];
}

// ================= column-local Chebyshev (ZERO per-step boundaries) =================
#define AP(r) ((r) + ((r)>>4))   // LDS pad

__device__ __forceinline__ float4 f4m3(float4 acc, float s0, const float4 v0,
                                       float s1, const float4 v1, float s2, const float4 v2) {
  acc.x += s0*v0.x + s1*v1.x + s2*v2.x;
  acc.y += s0*v0.y + s1*v1.y + s2*v2.y;
  acc.z += s0*v0.z + s1*v1.z + s2*v2.z;
  acc.w += s0*v0.w + s1*v1.w + s2*v2.w;
  return acc;
}

__global__ __launch_bounds__(256, 2) void k_chebcol(char* ws, int g) {
  const int* desc = (const int*)ws;
  const int ng = desc[g];
  const int live = 16*desc[48+g];
  const int c0 = 4*(int)blockIdx.x;
  if (c0 >= live) return;
  const int deg = d_DEG[g];
  const int tid = threadIdx.x;
  __shared__ float4 Asb[AP(4500)];
  const float4* HA = (const float4*)(ws + O_HA);
  const float4* HB = (const float4*)(ws + O_HB);
  const float*  HC = (const float*)(ws + O_HC);
  const double* ch = (const double*)(ws + O_CH);
  const float cc = (float)ch[0];
  const float hinv = (float)(1.0/ch[1]);
  const double* coefd = (const double*)(ws + O_COEF) + (size_t)g*COEFLD;
  const float g0 = (float)coefd[0];

  float4 Bv[18];
  float4 Yv[18];

  #pragma unroll
  for (int i = 0; i < 6; ++i) {
    int atom = tid + 256*i;
    if (atom < NA) {
      int rb = desc[5120 + atom];
      int arank = rb & 0xffff;
      int aband = rb >> 16;
      int jc0 = 3*arank;
      #pragma unroll
      for (int a = 0; a < 3; ++a) {
        float4 t0;
        int jc = jc0 + a;
        bool lv = (aband == g) && (jc < ng);
        t0.x = (lv && jc == c0+0) ? 1.0f : 0.0f;
        t0.y = (lv && jc == c0+1) ? 1.0f : 0.0f;
        t0.z = (lv && jc == c0+2) ? 1.0f : 0.0f;
        t0.w = (lv && jc == c0+3) ? 1.0f : 0.0f;
        Asb[AP(3*atom+a)] = t0;
        Yv[3*i+a] = make_float4(g0*t0.x, g0*t0.y, g0*t0.z, g0*t0.w);
        Bv[3*i+a] = make_float4(0.0f, 0.0f, 0.0f, 0.0f);
      }
    }
  }
  __syncthreads();

  for (int k = 1; k <= deg; ++k) {
    const float gam = (float)coefd[k];
    const bool first = (k == 1);
    #pragma unroll
    for (int i = 0; i < 6; ++i) {
      int atom = tid + 256*i;
      if (atom < NA) {
        float4 acc0 = make_float4(0,0,0,0), acc1 = acc0, acc2 = acc0;
        float4 xd0 = acc0, xd1 = acc0, xd2 = acc0;
        #pragma unroll 5
        for (int du = -32; du <= 32; ++du) {
          int q = atom + du;
          if (q < 0) q += NA; else if (q >= NA) q -= NA;
          int t = (du == 0) ? 0 : ((du > 0) ? du : 32 - du);
          size_t hidx = (size_t)t*NA + atom;
          float4 ha = HA[hidx];
          float4 hb = HB[hidx];
          float  hc = HC[hidx];
          int r = 3*q;
          float4 r0 = Asb[AP(r)];
          float4 r1 = Asb[AP(r+1)];
          float4 r2 = Asb[AP(r+2)];
          if (du == 0) { xd0 = r0; xd1 = r1; xd2 = r2; }
          acc0 = f4m3(acc0, ha.x, r0, ha.y, r1, ha.z, r2);
          acc1 = f4m3(acc1, ha.w, r0, hb.x, r1, hb.y, r2);
          acc2 = f4m3(acc2, hb.z, r0, hb.w, r1, hc,  r2);
        }
        #pragma unroll
        for (int a = 0; a < 3; ++a) {
          float4 accv = (a == 0) ? acc0 : ((a == 1) ? acc1 : acc2);
          float4 xdv  = (a == 0) ? xd0  : ((a == 1) ? xd1  : xd2);
          int bi = 3*i + a;
          float4 u, tn;
          u.x = (accv.x - cc*xdv.x)*hinv;
          u.y = (accv.y - cc*xdv.y)*hinv;
          u.z = (accv.z - cc*xdv.z)*hinv;
          u.w = (accv.w - cc*xdv.w)*hinv;
          tn.x = first ? u.x : (2.0f*u.x - Bv[bi].x);
          tn.y = first ? u.y : (2.0f*u.y - Bv[bi].y);
          tn.z = first ? u.z : (2.0f*u.z - Bv[bi].z);
          tn.w = first ? u.w : (2.0f*u.w - Bv[bi].w);
          Yv[bi].x += gam*tn.x;
          Yv[bi].y += gam*tn.y;
          Yv[bi].z += gam*tn.z;
          Yv[bi].w += gam*tn.w;
          Bv[bi] = tn;
        }
      }
    }
    __syncthreads();
    #pragma unroll
    for (int i = 0; i < 6; ++i) {
      int atom = tid + 256*i;
      if (atom < NA) {
        #pragma unroll
        for (int a = 0; a < 3; ++a) {
          int r = AP(3*atom+a);
          int bi = 3*i + a;
          float4 tmp = Asb[r];
          Asb[r] = Bv[bi];
          Bv[bi] = tmp;
        }
      }
    }
    __syncthreads();
  }

  double* X2 = (double*)(ws + O_X2);
  #pragma unroll
  for (int i = 0; i < 6; ++i) {
    int atom = tid + 256*i;
    if (atom < NA) {
      #pragma unroll
      for (int a = 0; a < 3; ++a) {
        int row = 3*atom + a;
        double* xr = X2 + (size_t)row*YLD;
        float4 y = Yv[3*i+a];
        if (c0+0 < live) xr[c0+0] = (c0+0 < ng) ? (double)y.x : 0.0;
        if (c0+1 < live) xr[c0+1] = (c0+1 < ng) ? (double)y.y : 0.0;
        if (c0+2 < live) xr[c0+2] = (c0+2 < ng) ? (double)y.z : 0.0;
        if (c0+3 < live) xr[c0+3] = (c0+3 < ng) ? (double)y.w : 0.0;
      }
    }
  }
}

// ---------------- f64 SpMM: Z = H * X(cols c0..c0+cw), clamped to live band width ------
__global__ __launch_bounds__(256) void k_spmm64(char* ws, const double* __restrict__ X,
                                                double* __restrict__ Z, int cw, int g, int cpos,
                                                int xld) {
  int live = 16*((const int*)ws)[48+g];
  if (xld < 0) xld = live;
  int cb = blockIdx.y*256;
  if (cpos + cb >= live) return;
  __shared__ double sval[585];
  __shared__ int scol[65];
  int p = blockIdx.x;
  const double* hv = (const double*)(ws + O_HV64) + (size_t)p*585;
  const int* hcol = (const int*)(ws + O_HCOL) + p*65;
  for (int l = threadIdx.x; l < 585; l += 256) sval[l] = hv[l];
  if (threadIdx.x < 65) scol[threadIdx.x] = hcol[threadIdx.x];
  __syncthreads();
  int col = cb + threadIdx.x;
  if (col >= cw || cpos + col >= live) return;
  double a0 = 0.0, a1 = 0.0, a2 = 0.0;
  for (int t = 0; t < 65; ++t) {
    int q = scol[t];
    const double* xb = X + (size_t)(3*q)*xld + col;
    double x0 = xb[0], x1 = xb[xld], x2 = xb[2*xld];
    const double* v = sval + t*9;
    a0 += v[0]*x0 + v[1]*x1 + v[2]*x2;
    a1 += v[3]*x0 + v[4]*x1 + v[5]*x2;
    a2 += v[6]*x0 + v[7]*x1 + v[8]*x2;
  }
  Z[(size_t)(3*p+0)*ZCHW + col] = a0;
  Z[(size_t)(3*p+1)*ZCHW + col] = a1;
  Z[(size_t)(3*p+2)*ZCHW + col] = a2;
}

// ---------------- f64 GEMMs (loads & writes clamped to Ml/Nl/Kl) ----------------
__global__ __launch_bounds__(256) void gemm_tn(const double* __restrict__ A, const double* __restrict__ B,
                                               double* __restrict__ C,
                                               int M, int N, int K, int lda, int ldb, int ldc,
                                               const int* __restrict__ nbp, int cm, int cn, int noff, int ck) {
  int live = nbp ? 16*nbp[0] : 0x7fffffff;
  if (lda < 0) lda = live;
  if (ldb < 0) ldb = live;
  if (ldc < 0) ldc = live;
  int Ml = (cm && live < M) ? live : M;
  int Nl = N;
  if (cn) { int nl = live - noff; Nl = (nl < N) ? nl : N; }
  int Kl = (ck && live < K) ? live : K;
  int i0 = blockIdx.x*64, j0 = blockIdx.y*64;
  if (i0 >= Ml || j0 >= Nl) return;
  __shared__ double As[16][66];
  __shared__ double Bs[16][66];
  int tid = threadIdx.x;
  int tx = tid & 15, ty = tid >> 4;
  double acc[4][4] = {};
  for (int k0 = 0; k0 < Kl; k0 += 16) {
    for (int l = tid; l < 1024; l += 256) {
      int r = l >> 6, c = l & 63;
      int kk = k0 + r;
      As[r][c] = (kk < Kl && i0+c < Ml) ? A[(size_t)kk*lda + i0+c] : 0.0;
    }
    for (int l = tid; l < 1024; l += 256) {
      int r = l >> 6, c = l & 63;
      int kk = k0 + r;
      Bs[r][c] = (kk < Kl && j0+c < Nl) ? B[(size_t)kk*ldb + j0+c] : 0.0;
    }
    __syncthreads();
    for (int kk = 0; kk < 16; ++kk) {
      double a[4], b[4];
      #pragma unroll
      for (int i = 0; i < 4; ++i) { a[i] = As[kk][4*ty+i]; b[i] = Bs[kk][4*tx+i]; }
      #pragma unroll
      for (int i = 0; i < 4; ++i)
        #pragma unroll
        for (int j = 0; j < 4; ++j) acc[i][j] += a[i]*b[j];
    }
    __syncthreads();
  }
  for (int i = 0; i < 4; ++i) {
    int ii = i0 + 4*ty + i;
    if (ii >= Ml) continue;
    for (int j = 0; j < 4; ++j) {
      int jj = j0 + 4*tx + j;
      if (jj < Nl) C[(size_t)ii*ldc + jj] = acc[i][j];
    }
  }
}

// fpb: fused Newton-Schulz P-build epilogue: C = (15*I - 10*A + 3*(A*B))/8  (A==B==S)
__global__ __launch_bounds__(256) void gemm_nn(const double* __restrict__ A, const double* __restrict__ B,
                                               double* __restrict__ C,
                                               int M, int N, int K, int lda, int ldb, int ldc,
                                               const int* __restrict__ nbp, int cm, int cn, int noff, int ck,
                                               int fpb) {
  int live = nbp ? 16*nbp[0] : 0x7fffffff;
  if (lda < 0) lda = live;
  if (ldb < 0) ldb = live;
  if (ldc < 0) ldc = live;
  int Ml = (cm && live < M) ? live : M;
  int Nl = N;
  if (cn) { int nl = live - noff; Nl = (nl < N) ? nl : N; }
  int Kl = (ck && live < K) ? live : K;
  int i0 = blockIdx.x*64, j0 = blockIdx.y*64;
  if (i0 >= Ml || j0 >= Nl) return;
  __shared__ double As[16][66];
  __shared__ double Bs[16][66];
  int tid = threadIdx.x;
  int tx = tid & 15, ty = tid >> 4;
  double acc[4][4] = {};
  for (int k0 = 0; k0 < Kl; k0 += 16) {
    for (int l = tid; l < 1024; l += 256) {
      int r = l & 15, c = l >> 4;
      As[r][c] = ((i0+c) < Ml && (k0+r) < Kl) ? A[(size_t)(i0+c)*lda + k0+r] : 0.0;
    }
    for (int l = tid; l < 1024; l += 256) {
      int r = l >> 6, c = l & 63;
      Bs[r][c] = ((k0+r) < Kl && (j0+c) < Nl) ? B[(size_t)(k0+r)*ldb + j0+c] : 0.0;
    }
    __syncthreads();
    for (int kk = 0; kk < 16; ++kk) {
      double a[4], b[4];
      #pragma unroll
      for (int i = 0; i < 4; ++i) { a[i] = As[kk][4*ty+i]; b[i] = Bs[kk][4*tx+i]; }
      #pragma unroll
      for (int i = 0; i < 4; ++i)
        #pragma unroll
        for (int j = 0; j < 4; ++j) acc[i][j] += a[i]*b[j];
    }
    __syncthreads();
  }
  for (int i = 0; i < 4; ++i) {
    int ii = i0 + 4*ty + i;
    if (ii >= Ml) continue;
    for (int j = 0; j < 4; ++j) {
      int jj = j0 + 4*tx + j;
      if (jj < Nl) {
        if (fpb) {
          double sv = A[(size_t)ii*lda + jj];
          C[(size_t)ii*ldc + jj] = (15.0*((ii==jj) ? 1.0 : 0.0) - 10.0*sv + 3.0*acc[i][j])*0.125;
        } else {
          C[(size_t)ii*ldc + jj] = acc[i][j];
        }
      }
    }
  }
}

// ---------------- Ptot init: copy live x live of P (ld=cap) into G_g scratch (ld=cap) ------
__global__ void k_ptinit(char* ws, int g, int cap) {
  int live = 16*((const int*)ws)[48+g];
  const double* P = (const double*)(ws + O_P);
  double* A = (double*)(ws + O_G) + goffd(g);
  size_t n = (size_t)live*live;
  for (size_t i = (size_t)blockIdx.x*256 + threadIdx.x; i < n; i += (size_t)gridDim.x*256) {
    int r = (int)(i / live), c = (int)(i % live);
    A[(size_t)r*cap + c] = P[(size_t)r*cap + c];
  }
}

// ---------------- per-band snapshot: Heff copy (G->Jbuf) + RB init (PD->RB) ----------------
__global__ void k_snap(char* ws, int g) {
  const int* desc = (const int*)ws;
  int live = 16*desc[48+g];
  int cap = (g < 8) ? CAPSM : CAP8;
  size_t n1 = (size_t)cap*live;
  size_t n2 = (size_t)live*9;
  const double* Gsrc = (const double*)(ws + O_G) + goffd(g);
  double* Jdst = (double*)(ws + O_J) + goffd(g);
  const double* PD = (const double*)(ws + O_PD) + (size_t)g*1152*9;
  double* RB = (double*)(ws + O_RB) + (size_t)g*1152*9;
  for (size_t i = (size_t)blockIdx.x*256 + threadIdx.x; i < n1 + n2; i += (size_t)gridDim.x*256) {
    if (i < n1) Jdst[i] = Gsrc[i];
    else RB[i - n1] = PD[i - n1];
  }
}

// ---------------- block one-sided Jacobi (R6-exact visit; PER-BAND barriers) ----------------
template<int L>
__device__ __forceinline__ int jacobi_visit(double* __restrict__ G, double* __restrict__ RBg,
    int cap, int ng, int live, int cI, int cJ,
    double* Wab, double* Vs, double* Rls,
    double* cc_, double* ss_, double* crr_, double* srr_,
    int* pp_, int* qq_, int* part_, int* isp_) {
  constexpr int ls = L/2;
  constexpr int P2 = L/2;
  constexpr int ldw = L + 1;
  constexpr int WSZ = 64*65;
  constexpr int AB = L/16;
  const int tid = threadIdx.x;
  const int tx = tid & 15, ty = tid >> 4;
  // ---- gram: W = [G_I|G_J]^T [G_I|G_J]  (Vs aliased as row-chunk staging) ----
  double w[AB][AB];
  #pragma unroll
  for (int a = 0; a < AB; ++a)
    #pragma unroll
    for (int b = 0; b < AB; ++b) w[a][b] = 0.0;
  for (int i0 = 0; i0 < ng; i0 += 64) {
    for (int e = tid; e < 64*L; e += 256) {
      int rw = e & 63, j = e >> 6;
      int cidx = (j < ls) ? (cI + j) : (cJ + (j - ls));
      int i = i0 + rw;
      Vs[rw*ldw + j] = (i < ng && cidx < live) ? G[(size_t)cidx*cap + i] : 0.0;
    }
    __syncthreads();
    #pragma unroll 4
    for (int rw = 0; rw < 64; ++rw) {
      double ra[AB], rb[AB];
      #pragma unroll
      for (int a = 0; a < AB; ++a) ra[a] = Vs[rw*ldw + ty + 16*a];
      #pragma unroll
      for (int b = 0; b < AB; ++b) rb[b] = Vs[rw*ldw + tx + 16*b];
      #pragma unroll
      for (int a = 0; a < AB; ++a)
        #pragma unroll
        for (int b = 0; b < AB; ++b) w[a][b] += ra[a]*rb[b];
    }
    __syncthreads();
  }
  #pragma unroll
  for (int a = 0; a < AB; ++a)
    #pragma unroll
    for (int b = 0; b < AB; ++b)
      Wab[(ty + 16*a)*ldw + tx + 16*b] = w[a][b];
  for (int e = tid; e < L*L; e += 256) {
    int r = e / L, c = e % L;
    Vs[r*ldw + c] = (r == c) ? 1.0 : 0.0;
  }
  __syncthreads();
  // ---- local two-sided Jacobi on W ----
  int cur = 0;
  int blockAny = 0;
  for (int sw = 0; sw < NSWLOC; ++sw) {
    int sweepAny = 0;
    for (int rr2 = 0; rr2 < L-1; ++rr2) {
      int myrot = 0;
      if (tid < P2) {
        int pid = tid, p2, q2;
        if (pid == 0) { p2 = L-1; q2 = rr2; }
        else { p2 = (rr2 + pid) % (L-1); q2 = (rr2 + (L-1) - pid) % (L-1); }
        const double* Wc = Wab + cur*WSZ;
        double wpp = Wc[p2*ldw+p2], wqq = Wc[q2*ldw+q2], wpq = Wc[p2*ldw+q2];
        bool rot = (wpq*wpq > 1e-28*fabs(wpp*wqq) + 1e-280);
        double cr = 1.0, sr = 0.0;
        if (rot) {
          double tau = (wqq - wpp)/(2.0*wpq);
          double tt = (tau >= 0.0 ? 1.0 : -1.0)/(fabs(tau) + sqrt(1.0 + tau*tau));
          cr = 1.0/sqrt(1.0 + tt*tt);
          sr = tt*cr;
        }
        pp_[pid] = p2; qq_[pid] = q2; cc_[pid] = cr; ss_[pid] = sr;
        part_[p2] = q2; part_[q2] = p2;
        isp_[p2] = 1;  isp_[q2] = 0;
        crr_[p2] = cr; crr_[q2] = cr;
        srr_[p2] = sr; srr_[q2] = sr;
        myrot = rot ? 1 : 0;
      }
      int any = __syncthreads_or(myrot);
      if (any) {
        sweepAny = 1;
        const double* Wc = Wab + cur*WSZ;
        double* Wn = Wab + (cur^1)*WSZ;
        #pragma unroll
        for (int jj = 0; jj < (L*P2)/256; ++jj) {
          int e = tid + 256*jj;
          int rw = e / P2, pid = e % P2;
          int p = pp_[pid], q = qq_[pid];
          double cr = cc_[pid], sr = ss_[pid];
          int prn = part_[rw];
          double crR = crr_[rw], srR = srr_[rw];
          int rowIsP = isp_[rw];
          double wrp = Wc[rw*ldw+p],  wrq = Wc[rw*ldw+q];
          double wop = Wc[prn*ldw+p], woq = Wc[prn*ldw+q];
          double rvp, rvq;
          if (rowIsP) { rvp = crR*wrp - srR*wop; rvq = crR*wrq - srR*woq; }
          else        { rvp = srR*wop + crR*wrp; rvq = srR*woq + crR*wrq; }
          Wn[rw*ldw+p] = cr*rvp - sr*rvq;
          Wn[rw*ldw+q] = sr*rvp + cr*rvq;
          double vp = Vs[rw*ldw+p], vq = Vs[rw*ldw+q];
          Vs[rw*ldw+p] = cr*vp - sr*vq;
          Vs[rw*ldw+q] = sr*vp + cr*vq;
        }
        __syncthreads();
        cur ^= 1;
      }
    }
    blockAny |= sweepAny;
    if (!sweepAny) break;
  }
  if (!blockAny) return 0;   // V == I exactly: R and panels unchanged
  // ---- R update: R_panel <- V^T R_panel ----
  for (int e = tid; e < L*9; e += 256) {
    int s = e/9, c = e - 9*s;
    int cidx = (s < ls) ? (cI + s) : (cJ + (s - ls));
    Rls[s*10 + c] = (cidx < live) ? RBg[(size_t)cidx*9 + c] : 0.0;
  }
  __syncthreads();
  for (int e = tid; e < L*9; e += 256) {
    int r = e/9, c = e - 9*r;
    int cidx = (r < ls) ? (cI + r) : (cJ + (r - ls));
    if (cidx < live) {
      double s = 0.0;
      #pragma unroll
      for (int s2 = 0; s2 < L; ++s2) s += Vs[s2*ldw + r]*Rls[s2*10 + c];
      RBg[(size_t)cidx*9 + c] = s;
    }
  }
  // ---- panel update: [G_I|G_J] <- [G_I|G_J] * V ----
  for (int i = tid; i < ng; i += 256) {
    double bg[L];
    #pragma unroll
    for (int rw = 0; rw < L; ++rw) {
      int cidx = (rw < ls) ? (cI + rw) : (cJ + (rw - ls));
      bg[rw] = (cidx < live) ? G[(size_t)cidx*cap + i] : 0.0;
    }
    for (int p = 0; p < L; ++p) {
      double s = 0.0;
      #pragma unroll
      for (int rw = 0; rw < L; ++rw) s += bg[rw]*Vs[rw*ldw + p];
      int cidx = (p < ls) ? (cI + p) : (cJ + (p - ls));
      if (cidx < live) G[(size_t)cidx*cap + i] = s;
    }
  }
  return 1;
}

// per-band sense-reversing barrier (device-scope atomics; blocks co-resident via coop launch)
__device__ __forceinline__ void band_barrier(int* arr, int* gen, int nblk) {
  __syncthreads();
  if (threadIdx.x == 0) {
    __threadfence();   // release: panel/flag writes visible before arrival
    int my = __hip_atomic_load(gen, __ATOMIC_RELAXED, __HIP_MEMORY_SCOPE_AGENT);
    int cnt = __hip_atomic_fetch_add(arr, 1, __ATOMIC_ACQ_REL, __HIP_MEMORY_SCOPE_AGENT);
    if (cnt == nblk - 1) {
      __hip_atomic_store(arr, 0, __ATOMIC_RELAXED, __HIP_MEMORY_SCOPE_AGENT);
      __hip_atomic_fetch_add(gen, 1, __ATOMIC_ACQ_REL, __HIP_MEMORY_SCOPE_AGENT);
    } else {
      while (__hip_atomic_load(gen, __ATOMIC_ACQUIRE, __HIP_MEMORY_SCOPE_AGENT) == my)
        __builtin_amdgcn_s_sleep(2);
    }
    __threadfence();   // acquire: other blocks' writes visible after release
  }
  __syncthreads();
}

__global__ __launch_bounds__(256) void k_bjac(char* ws) {
  const int* desc = (const int*)ws;
  int* sflag = (int*)ws + 7000;          // [NB][SWEEPSB] rotation flags (host-zeroed)
  int* barr  = (int*)ws + 7100;          // [NB] arrival counters (host-zeroed)
  int* bgen  = (int*)ws + 7120;          // [NB] generations (host-zeroed)
  double* Gb = (double*)(ws + O_G);
  __shared__ double Wab_s[2*64*65];
  __shared__ double Vs_s[64*65];
  __shared__ double Rls_s[64*10];
  __shared__ double cc_s[32], ss_s[32], crr_s[64], srr_s[64];
  __shared__ int pp_s[32], qq_s[32], part_s[64], isp_s[64];

  int t = blockIdx.x;
  int g = (t < 160) ? (t/20) : 8;
  int k = (t < 160) ? (t%20) : (t-160);
  int nb16 = desc[48+g];
  int live = 16*nb16;
  int ng = desc[g];
  int ls, nbL;
  if (g < 8) { ls = 16; nbL = nb16; }
  else       { ls = 32; nbL = (nb16 + 1) >> 1; nbL += (nbL & 1); }
  int m = (nbL >= 2) ? nbL - 1 : 1;
  int cap = (g < 8) ? CAPSM : CAP8;
  double* G = Gb + goffd(g);
  double* RBg = (double*)(ws + O_RB) + (size_t)g*1152*9;
  bool bandDone = (nbL < 2);
  int RTg = SWEEPSB*m;

  for (int r = 0; r < RTg; ++r) {
    // band-sweep convergence check (uniform: all band blocks read identical
    // post-barrier sflag state via device-scope RMW) -> whole band exits together
    if (!bandDone && r > 0) {
      int rp = r - 1;
      if ((rp % m) == m-1) {
        int s = rp/m;
        if (atomicOr(&sflag[g*SWEEPSB + s], 0) == 0) bandDone = true;
      }
    }
    if (bandDone) break;
    bool active = (k < nbL/2);
    int cI = 0, cJ = 0;
    if (active) {
      int rr = r % m;
      int I, J;
      if (k == 0) { I = m; J = rr; }
      else { I = (rr + k) % m; J = (rr + m - k) % m; }
      cI = I*ls; cJ = J*ls;
      if (cI >= live && cJ >= live) active = false;
    }
    if (active) {
      int did;
      if (g < 8)
        did = jacobi_visit<32>(G, RBg, cap, ng, live, cI, cJ, Wab_s, Vs_s, Rls_s,
                               cc_s, ss_s, crr_s, srr_s, pp_s, qq_s, part_s, isp_s);
      else
        did = jacobi_visit<64>(G, RBg, cap, ng, live, cI, cJ, Wab_s, Vs_s, Rls_s,
                               cc_s, ss_s, crr_s, srr_s, pp_s, qq_s, part_s, isp_s);
      if (did && threadIdx.x == 0) atomicOr(&sflag[g*SWEEPSB + r/m], 1);
    }
    band_barrier(&barr[g], &bgen[g], 20);
  }
}

// ---------------- eigenvalues: Rayleigh lambda_k = (G_k . HG_k)/(G_k . G_k) ----------------
__global__ void k_eig(char* ws) {
  const int* desc = (const int*)ws;
  double* eva = (double*)(ws + O_EVA);
  int* sid = (int*)(ws + O_SID);
  int wv = (blockIdx.x*blockDim.x + threadIdx.x) >> 6;
  int lane = threadIdx.x & 63;
  if (wv >= SORTN) return;
  if (wv >= NDIM) {
    if (lane == 0) { eva[wv] = 1e300; sid[wv] = wv; }
    return;
  }
  int g = 0;
  while (g < 8 && wv >= desc[16+g+1]) ++g;
  int k = wv - desc[16+g];
  int cap = (g < 8) ? CAPSM : CAP8;
  int ng = desc[g];
  size_t base = goffd(g) + (size_t)k*cap;
  const double* G = (const double*)(ws + O_G) + base;
  const double* HG = (const double*)(ws + O_X1) + base;
  double d1 = 0.0, d2 = 0.0;
  for (int i = lane; i < ng; i += 64) {
    double gv = G[i];
    d1 += gv*HG[i];
    d2 += gv*gv;
  }
  for (int s = 32; s > 0; s >>= 1) {
    d1 += __shfl_xor(d1, s, 64);
    d2 += __shfl_xor(d2, s, 64);
  }
  if (lane == 0) {
    eva[wv] = (d2 > 0.0) ? d1/d2 : 0.0;
    sid[wv] = wv;
  }
}

// ---------------- single-block bitonic sort ----------------
__global__ void k_sort(char* ws) {
  double* key = (double*)(ws + O_EVA);
  int* val = (int*)(ws + O_SID);
  int tid = threadIdx.x;
  for (int size = 2; size <= SORTN; size <<= 1) {
    for (int stride = size >> 1; stride > 0; stride >>= 1) {
      __syncthreads();
      for (int t = tid; t < SORTN/2; t += 1024) {
        int i = 2*t - (t & (stride-1));
        int j = i + stride;
        bool up = ((i & size) == 0);
        double ki = key[i], kj = key[j];
        if ((ki > kj) == up) {
          key[i] = kj; key[j] = ki;
          int v = val[i]; val[i] = val[j]; val[j] = v;
        }
      }
    }
  }
}

// ---------------- final: freq, ir, raman ----------------
__global__ void k_final(char* ws, float* __restrict__ out) {
  int m = blockIdx.x*256 + threadIdx.x;
  if (m >= NOUT) return;
  const int* desc = (const int*)ws;
  const double* eva = (const double*)(ws + O_EVA);
  const int* sid = (const int*)(ws + O_SID);
  int s = m + 6;
  double lam = eva[s];
  int gid = sid[s];
  int g = 0;
  while (g < 8 && gid >= desc[16+g+1]) ++g;
  int k = gid - desc[16+g];
  const double* R = (const double*)(ws + O_RB) + ((size_t)g*1152 + k)*9;
  double q0 = R[0], q1 = R[1], q2 = R[2];
  double ir = 42.2561*(q0*q0 + q1*q1 + q2*q2);
  double xx = R[3], xy = R[4], yy = R[5], xz = R[6], zy = R[7], zz = R[8];
  double alpha = (xx + yy + zz)/3.0;
  double gsq = 0.5*((xx-yy)*(xx-yy) + (yy-zz)*(yy-zz) + (zz-xx)*(zz-xx))
             + 3.0*(xy*xy + xz*xz + zy*zy);
  double raman = (45.0*alpha*alpha + 7.0*gsq)*0.078424;
  double freq = sqrt(fmax(lam, 0.0)*9.375829e28)/(2.0*PI_D)/2.9979245800e10*0.965;
  out[m] = (float)freq;
  out[NOUT + m] = (float)ir;
  out[2*NOUT + m] = (float)raman;
}

__global__ void k_fail(float* out) {
  int i = blockIdx.x*256 + threadIdx.x;
  if (i < 3*NOUT) out[i] = -7777.0f;
}

// ---------------- host ----------------
extern "C" void kernel_launch(void* const* d_in, const int* in_sizes, int n_in,
                              void* d_out, int out_size, void* d_ws, size_t ws_size,
                              hipStream_t stream) {
  const int* z = (const int*)d_in[1];
  const int* ei = (const int*)d_in[2];
  const float* Hi = (const float*)d_in[3];
  const float* Hij = (const float*)d_in[4];
  const float* ded = (const float*)d_in[5];
  const float* dep = (const float*)d_in[6];
  float* out = (float*)d_out;
  char* ws = (char*)d_ws;

  if (ws_size < WS_NEED) {
    k_fail<<<(3*NOUT+255)/256, 256, 0, stream>>>(out);
    return;
  }

  hipMemsetAsync(ws, 0, O_HCOL, stream);
  k_prep<<<1, 256, 0, stream>>>(z, ws);
  k_buildH<<<NA, 128, 0, stream>>>(ei, Hi, Hij, ws);
  k_coeff<<<1, 256, 0, stream>>>(ws);
  k_dt<<<(NDIM+255)/256, 256, 0, stream>>>(ded, dep, ws);

  double* X1 = (double*)(ws + O_X1);    // ortho X, ld=YLD
  double* X2 = (double*)(ws + O_X2);    // cheb output, ld=YLD
  double* Sb = (double*)(ws + O_S);
  double* Pb = (double*)(ws + O_P);
  double* Zb = (double*)(ws + O_S);     // Z chunk aliases S (S dead after NS chain)
  double* Dt = (double*)(ws + O_DT);

  for (int g = 0; g < NB; ++g) {
    int cap = capb(g);
    const int* nbp = ((const int*)(ws)) + 48 + g;
    dim3 gsq((cap+63)/64, (cap+63)/64);
    double* Ag = (double*)(ws + O_G) + goffd(g);   // Ptot ping (dead until Heff)
    double* Bg = (double*)(ws + O_J) + goffd(g);   // Ptot pong (dead until snapshot)

    // ---- column-local Chebyshev -> X2 ----
    k_chebcol<<<dim3((cap+3)/4), 256, 0, stream>>>(ws, g);

    // ---- small-matrix Newton-Schulz on live x live; accumulate Ptot in Ag/Bg ----
    gemm_tn<<<gsq, 256, 0, stream>>>(X2, X2, Sb, cap, cap, NDIM, YLD, YLD, cap, nbp, 1, 1, 0, 0);
    for (int it = 0; it < 5; ++it) {
      gemm_nn<<<gsq, 256, 0, stream>>>(Sb, Sb, Pb, cap, cap, cap, cap, cap, cap, nbp, 1, 1, 0, 1, 1);
      if (it == 0) {
        k_ptinit<<<1024, 256, 0, stream>>>(ws, g, cap);        // Ptot(A) = P1
      } else {
        double* src = (it & 1) ? Ag : Bg;
        double* dst = (it & 1) ? Bg : Ag;
        gemm_nn<<<gsq, 256, 0, stream>>>(src, Pb, dst, cap, cap, cap, cap, cap, cap, nbp, 1, 1, 0, 1, 0);
      }
      if (it < 4) {
        double* Ct = (it & 1) ? Ag : Bg;
        gemm_nn<<<gsq, 256, 0, stream>>>(Sb, Pb, Ct, cap, cap, cap, cap, cap, cap, nbp, 1, 1, 0, 1, 0);
        gemm_nn<<<gsq, 256, 0, stream>>>(Pb, Ct, Sb, cap, cap, cap, cap, cap, cap, nbp, 1, 1, 0, 1, 0);
      }
    }
    // X_ortho = X * Ptot  (Ptot in Ag after it=4)
    gemm_nn<<<dim3((NDIM+63)/64, (cap+63)/64), 256, 0, stream>>>(
        X2, Ag, X1, NDIM, cap, cap, YLD, cap, YLD, nbp, 0, 1, 0, 1, 0);

    // ---- PD_g = X^T Dt ----
    gemm_tn<<<dim3((cap+63)/64, 1), 256, 0, stream>>>(X1, Dt,
        (double*)(ws + O_PD) + (size_t)g*1152*9, cap, 9, NDIM, YLD, 9, 9, nbp, 1, 0, 0, 0);
    // ---- Heff_g = X^T (H X), chunked (overwrites Ag AFTER its last use above) ----
    for (int zc = 0; zc < 2; ++zc) {
      int c0 = zc*ZCHW;
      int cwz = cap - c0; if (cwz > ZCHW) cwz = ZCHW;
      if (cwz <= 0) break;
      dim3 gz(NA, (cwz + 255)/256);
      k_spmm64<<<gz, 256, 0, stream>>>(ws, X1 + c0, Zb, cwz, g, c0, YLD);
      gemm_tn<<<dim3((cap+63)/64, (cwz+63)/64), 256, 0, stream>>>(X1, Zb, Ag + c0,
          cap, cwz, NDIM, YLD, ZCHW, cap, nbp, 1, 1, c0, 0);
    }
    // snapshot Heff -> Jbuf (overwrites Bg scratch), PD -> RB
    k_snap<<<2048, 256, 0, stream>>>(ws, g);
  }

  // joint block one-sided Jacobi on all bands (per-band barriers; bands run concurrently)
  {
    void* args[] = { (void*)&ws };
    hipLaunchCooperativeKernel((void*)k_bjac, dim3(TSLOTS), dim3(256), args, 0, stream);
  }

  // HG_g = G_g(final) x Heff_snapshot  (Rayleigh numerator), per band
  for (int g = 0; g < NB; ++g) {
    int cap = capb(g);
    const int* nbp = ((const int*)(ws)) + 48 + g;
    gemm_nn<<<dim3((cap+63)/64, (cap+63)/64), 256, 0, stream>>>(
        (double*)(ws + O_G) + goffd(g),
        (double*)(ws + O_J) + goffd(g),
        (double*)(ws + O_X1) + goffd(g),
        cap, cap, cap, cap, cap, cap, nbp, 1, 1, 0, 1, 0);
  }

  k_eig<<<(SORTN*64)/256, 256, 0, stream>>>(ws);
  k_sort<<<1, 1024, 0, stream>>>(ws);
  k_final<<<(NOUT+255)/256, 256, 0, stream>>>(ws, out);
}

// Round 12
// 398190.405 us; speedup vs baseline: 1.0635x; 1.0635x over previous
//
#include <hip/hip_runtime.h>
#include <hip/hip_cooperative_groups.h>
#include <math.h>

namespace cg = cooperative_groups;

#define NA      1500
#define NEDGE   48000
#define NDIM    4500
#define NB      9
#define ZCHW    576
#define YLD     1152
#define CAPSM   640
#define CAP8    1152
#define SWEEPSB 8
#define NSWLOC  8
#define TSLOTS  180
#define SORTN   8192
#define COEFLD  864
#define NOUT    4494
#define PI_D    3.14159265358979323846

// Chebyshev filter degrees
static const int H_DEG[NB] = {24, 48, 96, 160, 320, 320, 336, 336, 272};
__device__ __constant__ int d_DEG[NB] = {24, 48, 96, 160, 320, 320, 336, 336, 272};
__device__ __constant__ double d_MASS[10] = {1.008,4.003,6.941,9.012,10.811,12.011,14.007,15.999,18.998,20.18};
__device__ __constant__ double d_BLO[NB] = {31.04695, 9.84715, 6.37590, 5.08655, 4.39385, 3.86620, 3.34740, 2.87855, -1.0e9};
__device__ __constant__ double d_BHI[NB] = {1.0e9, 31.04695, 9.84715, 6.37590, 5.08655, 4.39385, 3.86620, 3.34740, 2.87855};

// ---------------- workspace layout (bytes) ----------------
constexpr size_t O_DESC = 0;
constexpr size_t O_WM   = 32768;
constexpr size_t O_MINV = O_WM + 12288;
constexpr size_t O_GER  = O_MINV + 12288;
constexpr size_t O_CH   = O_GER + 24576;
constexpr size_t O_COEF = O_CH + 256;
constexpr size_t O_DT   = O_COEF + (size_t)NB*COEFLD*8;
constexpr size_t O_PD   = O_DT + (size_t)NDIM*9*8;
constexpr size_t O_RB   = O_PD + (size_t)NB*1152*9*8;
constexpr size_t O_EVA  = O_RB + (size_t)NB*1152*9*8;
constexpr size_t O_SID  = O_EVA + (size_t)SORTN*8;
constexpr size_t O_HCOL = O_SID + (size_t)SORTN*4;
constexpr size_t O_HV64 = O_HCOL + (size_t)NA*65*4;      // f64[1500*65*9] (spmm64)
constexpr size_t O_HV32 = O_HV64 + (size_t)NA*65*9*8;    // (reserved; legacy spacing)
constexpr size_t O_Y    = O_HV32 + (size_t)NA*65*12*4;   // hosts HA/HB/HC f32 transposed H
constexpr size_t O_HA   = O_Y;                           // float4[65*1500]  h[0..3]
constexpr size_t O_HB   = O_HA + (size_t)65*NA*16;       // float4[65*1500]  h[4..7]
constexpr size_t O_HC   = O_HB + (size_t)65*NA*16;       // float [65*1500]  h[8]
constexpr size_t O_X1   = O_Y + (size_t)NDIM*YLD*4;      // ortho X (ld=YLD); HG scratch after bjac
constexpr size_t O_X2   = O_X1 + (size_t)NDIM*YLD*8;     // cheb output (ld=YLD)
constexpr size_t O_S    = O_X2 + (size_t)NDIM*YLD*8;     // S; Z chunk aliases S after NS
constexpr size_t O_P    = O_S + (size_t)CAP8*CAP8*8;     // P
constexpr size_t O_G    = O_P + (size_t)CAP8*CAP8*8;     // Heff; during NS: Ptot ping scratch
constexpr size_t GTOT   = (size_t)8*CAPSM*CAPSM + (size_t)CAP8*CAP8;
constexpr size_t O_J    = O_G + GTOT*8;                  // Heff snapshot; during NS: Ptot pong
constexpr size_t WS_NEED = O_J + GTOT*8;                 // ~213 MB

__host__ __device__ inline size_t goffd(int g){ return (g < 8) ? (size_t)g*CAPSM*CAPSM : (size_t)8*CAPSM*CAPSM; }
__host__ inline int capb(int g){ return (g < 8) ? CAPSM : CAP8; }

// ---------------- prep ----------------
__global__ void k_prep(const int* __restrict__ z, char* ws) {
  int* desc = (int*)ws;
  double* wm = (double*)(ws + O_WM);
  double* minv = (double*)(ws + O_MINV);
  __shared__ int zb[NA];
  __shared__ int cnt[NB];
  int tid = threadIdx.x;
  if (tid < NB) cnt[tid] = 0;
  __syncthreads();
  for (int a = tid; a < NA; a += blockDim.x) {
    int zz = z[a];
    int b = (zz >= 8) ? 8 : zz;
    zb[a] = b;
    atomicAdd(&cnt[b], 1);
    double m = d_MASS[zz];
    wm[a] = 1.0/sqrt(m);
    minv[a] = 1.0/m;
  }
  __syncthreads();
  if (tid == 0) {
    int off = 0;
    for (int g = 0; g < NB; ++g) {
      desc[16+g] = 3*off;
      int ng = 3*cnt[g];
      int cap = (g < 8) ? CAPSM : CAP8;
      ng = (ng > cap) ? cap : ng;
      desc[g] = ng;
      desc[32+g] = ng + (ng & 1);
      int nb = (ng + 15)/16;
      if (nb & 1) nb++;
      desc[48+g] = nb;
      off += cnt[g];
    }
    desc[16+NB] = 3*off;
  }
  __syncthreads();
  for (int a = tid; a < NA; a += blockDim.x) {
    int b = zb[a]; int r = 0;
    for (int x = 0; x < a; ++x) r += (zb[x] == b) ? 1 : 0;
    if (r < 512) desc[64 + b*512 + r] = a;
    desc[5120 + a] = (r & 0xffff) | (b << 16);   // atom -> (rank, band)
  }
}

// ---------------- build sparse mass-weighted symmetrized H ----------------
__global__ void k_buildH(const int* __restrict__ ei, const float* __restrict__ Hi,
                         const float* __restrict__ Hij, char* ws) {
  int p = blockIdx.x, t = threadIdx.x;
  const double* wm = (const double*)(ws + O_WM);
  const double* minv = (const double*)(ws + O_MINV);
  int* hcol = (int*)(ws + O_HCOL);
  double* hv = (double*)(ws + O_HV64);
  float4* HAp = (float4*)(ws + O_HA);
  float4* HBp = (float4*)(ws + O_HB);
  float*  HCp = (float*)(ws + O_HC);
  __shared__ double rowabs[3][72];
  __shared__ double dcen[3];
  double v[9];
  int q = -1;
  if (t == 0) {
    q = p;
    double mi = minv[p];
    for (int a = 0; a < 3; ++a)
      for (int b = 0; b < 3; ++b)
        v[3*a+b] = 0.5*((double)Hi[9*p+3*a+b] + (double)Hi[9*p+3*b+a])*mi;
    for (int a = 0; a < 3; ++a) dcen[a] = v[3*a+a];
  } else if (t <= 32) {
    int off = t;
    int e = 32*p + off - 1;
    q = ei[e];
    double ww = 0.5*wm[p]*wm[q];
    for (int a = 0; a < 3; ++a)
      for (int b = 0; b < 3; ++b)
        v[3*a+b] = ww*(double)Hij[9*e+3*a+b];
  } else if (t <= 64) {
    int off = t - 32;
    int qr = (p + NA - off) % NA;
    int e = 32*qr + off - 1;
    q = ei[NEDGE + e];
    double ww = 0.5*wm[p]*wm[q];
    for (int a = 0; a < 3; ++a)
      for (int b = 0; b < 3; ++b)
        v[3*a+b] = ww*(double)Hij[9*e+3*b+a];
  }
  if (t < 65) {
    hcol[p*65+t] = q;
    for (int k = 0; k < 9; ++k)
      hv[((size_t)p*65+t)*9+k] = v[k];
    HAp[(size_t)t*NA + p] = make_float4((float)v[0],(float)v[1],(float)v[2],(float)v[3]);
    HBp[(size_t)t*NA + p] = make_float4((float)v[4],(float)v[5],(float)v[6],(float)v[7]);
    HCp[(size_t)t*NA + p] = (float)v[8];
    for (int a = 0; a < 3; ++a)
      rowabs[a][t] = fabs(v[3*a]) + fabs(v[3*a+1]) + fabs(v[3*a+2]);
  }
  __syncthreads();
  if (t == 0) {
    double hi = -1e300, lo = 1e300;
    for (int a = 0; a < 3; ++a) {
      double s = 0.0;
      for (int k = 0; k < 65; ++k) s += rowabs[a][k];
      double rad = s - fabs(dcen[a]);
      hi = fmax(hi, dcen[a] + rad);
      lo = fmin(lo, dcen[a] - rad);
    }
    double* ger = (double*)(ws + O_GER);
    ger[2*p] = hi; ger[2*p+1] = lo;
  }
}

// ---------------- spectrum bounds + Jackson-Chebyshev coefficients ----------------
__global__ void k_coeff(char* ws) {
  __shared__ double shi[256], slo[256];
  int tid = threadIdx.x;
  const double* ger = (const double*)(ws + O_GER);
  double hi = -1e300, lo = 1e300;
  for (int i = tid; i < NA; i += 256) { hi = fmax(hi, ger[2*i]); lo = fmin(lo, ger[2*i+1]); }
  shi[tid] = hi; slo[tid] = lo;
  __syncthreads();
  for (int s = 128; s > 0; s >>= 1) {
    if (tid < s) { shi[tid] = fmax(shi[tid], shi[tid+s]); slo[tid] = fmin(slo[tid], slo[tid+s]); }
    __syncthreads();
  }
  double* ch = (double*)(ws + O_CH);
  if (tid == 0) {
    double c = 0.5*(shi[0]+slo[0]);
    double h = 0.5*(shi[0]-slo[0])*1.002;
    ch[0] = c; ch[1] = h;
  }
  __syncthreads();
  double c = ch[0], h = ch[1];
  double* coef = (double*)(ws + O_COEF);
  for (int g = 0; g < NB; ++g) {
    int d = d_DEG[g];
    double xlo = fmin(1.0, fmax(-1.0, (d_BLO[g]-c)/h));
    double xhi = fmin(1.0, fmax(-1.0, (d_BHI[g]-c)/h));
    double f1 = acos(xlo), f2 = acos(xhi);
    double alp = PI_D/(double)(d+1);
    double ct = cos(alp)/sin(alp);
    for (int k = tid; k <= d; k += 256) {
      double ck = (k == 0) ? (f1-f2)/PI_D : 2.0*(sin(k*f1)-sin(k*f2))/(k*PI_D);
      double jk = ((double)(d+1-k)*cos(k*alp) + sin(k*alp)*ct)/(double)(d+1);
      coef[g*COEFLD+k] = ck*jk;
    }
  }
}

// ---------------- mass-weighted dipole/polar matrix Dt[4500][9] ----------------
__global__ void k_dt(const float* __restrict__ ded, const float* __restrict__ dep, char* ws) {
  int row = blockIdx.x*256 + threadIdx.x;
  if (row >= NDIM) return;
  int p = row/3, a = row%3;
  const double* wm = (const double*)(ws + O_WM);
  double w = wm[p];
  double* dt = (double*)(ws + O_DT) + (size_t)row*9;
  for (int cI = 0; cI < 3; ++cI) dt[cI] = w*(double)ded[9*p+3*a+cI];
  for (int cI = 0; cI < 6; ++cI) dt[3+cI] = w*(double)dep[18*p+6*a+cI];
}

// ================= column-local Chebyshev (ZERO per-step boundaries) =================
#define AP(r) ((r) + ((r)>>4))   // LDS pad

__device__ __forceinline__ float4 f4m3(float4 acc, float s0, const float4 v0,
                                       float s1, const float4 v1, float s2, const float4 v2) {
  acc.x += s0*v0.x + s1*v1.x + s2*v2.x;
  acc.y += s0*v0.y + s1*v1.y + s2*v2.y;
  acc.z += s0*v0.z + s1*v1.z + s2*v2.z;
  acc.w += s0*v0.w + s1*v1.w + s2*v2.w;
  return acc;
}

__global__ __launch_bounds__(256, 2) void k_chebcol(char* ws, int g) {
  const int* desc = (const int*)ws;
  const int ng = desc[g];
  const int live = 16*desc[48+g];
  const int c0 = 4*(int)blockIdx.x;
  if (c0 >= live) return;
  const int deg = d_DEG[g];
  const int tid = threadIdx.x;
  __shared__ float4 Asb[AP(4500)];
  const float4* HA = (const float4*)(ws + O_HA);
  const float4* HB = (const float4*)(ws + O_HB);
  const float*  HC = (const float*)(ws + O_HC);
  const double* ch = (const double*)(ws + O_CH);
  const float cc = (float)ch[0];
  const float hinv = (float)(1.0/ch[1]);
  const double* coefd = (const double*)(ws + O_COEF) + (size_t)g*COEFLD;
  const float g0 = (float)coefd[0];

  float4 Bv[18];
  float4 Yv[18];

  #pragma unroll
  for (int i = 0; i < 6; ++i) {
    int atom = tid + 256*i;
    if (atom < NA) {
      int rb = desc[5120 + atom];
      int arank = rb & 0xffff;
      int aband = rb >> 16;
      int jc0 = 3*arank;
      #pragma unroll
      for (int a = 0; a < 3; ++a) {
        float4 t0;
        int jc = jc0 + a;
        bool lv = (aband == g) && (jc < ng);
        t0.x = (lv && jc == c0+0) ? 1.0f : 0.0f;
        t0.y = (lv && jc == c0+1) ? 1.0f : 0.0f;
        t0.z = (lv && jc == c0+2) ? 1.0f : 0.0f;
        t0.w = (lv && jc == c0+3) ? 1.0f : 0.0f;
        Asb[AP(3*atom+a)] = t0;
        Yv[3*i+a] = make_float4(g0*t0.x, g0*t0.y, g0*t0.z, g0*t0.w);
        Bv[3*i+a] = make_float4(0.0f, 0.0f, 0.0f, 0.0f);
      }
    }
  }
  __syncthreads();

  for (int k = 1; k <= deg; ++k) {
    const float gam = (float)coefd[k];
    const bool first = (k == 1);
    #pragma unroll
    for (int i = 0; i < 6; ++i) {
      int atom = tid + 256*i;
      if (atom < NA) {
        float4 acc0 = make_float4(0,0,0,0), acc1 = acc0, acc2 = acc0;
        float4 xd0 = acc0, xd1 = acc0, xd2 = acc0;
        #pragma unroll 5
        for (int du = -32; du <= 32; ++du) {
          int q = atom + du;
          if (q < 0) q += NA; else if (q >= NA) q -= NA;
          int t = (du == 0) ? 0 : ((du > 0) ? du : 32 - du);
          size_t hidx = (size_t)t*NA + atom;
          float4 ha = HA[hidx];
          float4 hb = HB[hidx];
          float  hc = HC[hidx];
          int r = 3*q;
          float4 r0 = Asb[AP(r)];
          float4 r1 = Asb[AP(r+1)];
          float4 r2 = Asb[AP(r+2)];
          if (du == 0) { xd0 = r0; xd1 = r1; xd2 = r2; }
          acc0 = f4m3(acc0, ha.x, r0, ha.y, r1, ha.z, r2);
          acc1 = f4m3(acc1, ha.w, r0, hb.x, r1, hb.y, r2);
          acc2 = f4m3(acc2, hb.z, r0, hb.w, r1, hc,  r2);
        }
        #pragma unroll
        for (int a = 0; a < 3; ++a) {
          float4 accv = (a == 0) ? acc0 : ((a == 1) ? acc1 : acc2);
          float4 xdv  = (a == 0) ? xd0  : ((a == 1) ? xd1  : xd2);
          int bi = 3*i + a;
          float4 u, tn;
          u.x = (accv.x - cc*xdv.x)*hinv;
          u.y = (accv.y - cc*xdv.y)*hinv;
          u.z = (accv.z - cc*xdv.z)*hinv;
          u.w = (accv.w - cc*xdv.w)*hinv;
          tn.x = first ? u.x : (2.0f*u.x - Bv[bi].x);
          tn.y = first ? u.y : (2.0f*u.y - Bv[bi].y);
          tn.z = first ? u.z : (2.0f*u.z - Bv[bi].z);
          tn.w = first ? u.w : (2.0f*u.w - Bv[bi].w);
          Yv[bi].x += gam*tn.x;
          Yv[bi].y += gam*tn.y;
          Yv[bi].z += gam*tn.z;
          Yv[bi].w += gam*tn.w;
          Bv[bi] = tn;
        }
      }
    }
    __syncthreads();
    #pragma unroll
    for (int i = 0; i < 6; ++i) {
      int atom = tid + 256*i;
      if (atom < NA) {
        #pragma unroll
        for (int a = 0; a < 3; ++a) {
          int r = AP(3*atom+a);
          int bi = 3*i + a;
          float4 tmp = Asb[r];
          Asb[r] = Bv[bi];
          Bv[bi] = tmp;
        }
      }
    }
    __syncthreads();
  }

  double* X2 = (double*)(ws + O_X2);
  #pragma unroll
  for (int i = 0; i < 6; ++i) {
    int atom = tid + 256*i;
    if (atom < NA) {
      #pragma unroll
      for (int a = 0; a < 3; ++a) {
        int row = 3*atom + a;
        double* xr = X2 + (size_t)row*YLD;
        float4 y = Yv[3*i+a];
        if (c0+0 < live) xr[c0+0] = (c0+0 < ng) ? (double)y.x : 0.0;
        if (c0+1 < live) xr[c0+1] = (c0+1 < ng) ? (double)y.y : 0.0;
        if (c0+2 < live) xr[c0+2] = (c0+2 < ng) ? (double)y.z : 0.0;
        if (c0+3 < live) xr[c0+3] = (c0+3 < ng) ? (double)y.w : 0.0;
      }
    }
  }
}

// ---------------- f64 SpMM: Z = H * X(cols c0..c0+cw), clamped to live band width ------
__global__ __launch_bounds__(256) void k_spmm64(char* ws, const double* __restrict__ X,
                                                double* __restrict__ Z, int cw, int g, int cpos,
                                                int xld) {
  int live = 16*((const int*)ws)[48+g];
  if (xld < 0) xld = live;
  int cb = blockIdx.y*256;
  if (cpos + cb >= live) return;
  __shared__ double sval[585];
  __shared__ int scol[65];
  int p = blockIdx.x;
  const double* hv = (const double*)(ws + O_HV64) + (size_t)p*585;
  const int* hcol = (const int*)(ws + O_HCOL) + p*65;
  for (int l = threadIdx.x; l < 585; l += 256) sval[l] = hv[l];
  if (threadIdx.x < 65) scol[threadIdx.x] = hcol[threadIdx.x];
  __syncthreads();
  int col = cb + threadIdx.x;
  if (col >= cw || cpos + col >= live) return;
  double a0 = 0.0, a1 = 0.0, a2 = 0.0;
  for (int t = 0; t < 65; ++t) {
    int q = scol[t];
    const double* xb = X + (size_t)(3*q)*xld + col;
    double x0 = xb[0], x1 = xb[xld], x2 = xb[2*xld];
    const double* v = sval + t*9;
    a0 += v[0]*x0 + v[1]*x1 + v[2]*x2;
    a1 += v[3]*x0 + v[4]*x1 + v[5]*x2;
    a2 += v[6]*x0 + v[7]*x1 + v[8]*x2;
  }
  Z[(size_t)(3*p+0)*ZCHW + col] = a0;
  Z[(size_t)(3*p+1)*ZCHW + col] = a1;
  Z[(size_t)(3*p+2)*ZCHW + col] = a2;
}

// ---------------- f64 GEMMs (loads & writes clamped to Ml/Nl/Kl) ----------------
__global__ __launch_bounds__(256) void gemm_tn(const double* __restrict__ A, const double* __restrict__ B,
                                               double* __restrict__ C,
                                               int M, int N, int K, int lda, int ldb, int ldc,
                                               const int* __restrict__ nbp, int cm, int cn, int noff, int ck) {
  int live = nbp ? 16*nbp[0] : 0x7fffffff;
  if (lda < 0) lda = live;
  if (ldb < 0) ldb = live;
  if (ldc < 0) ldc = live;
  int Ml = (cm && live < M) ? live : M;
  int Nl = N;
  if (cn) { int nl = live - noff; Nl = (nl < N) ? nl : N; }
  int Kl = (ck && live < K) ? live : K;
  int i0 = blockIdx.x*64, j0 = blockIdx.y*64;
  if (i0 >= Ml || j0 >= Nl) return;
  __shared__ double As[16][66];
  __shared__ double Bs[16][66];
  int tid = threadIdx.x;
  int tx = tid & 15, ty = tid >> 4;
  double acc[4][4] = {};
  for (int k0 = 0; k0 < Kl; k0 += 16) {
    for (int l = tid; l < 1024; l += 256) {
      int r = l >> 6, c = l & 63;
      int kk = k0 + r;
      As[r][c] = (kk < Kl && i0+c < Ml) ? A[(size_t)kk*lda + i0+c] : 0.0;
    }
    for (int l = tid; l < 1024; l += 256) {
      int r = l >> 6, c = l & 63;
      int kk = k0 + r;
      Bs[r][c] = (kk < Kl && j0+c < Nl) ? B[(size_t)kk*ldb + j0+c] : 0.0;
    }
    __syncthreads();
    for (int kk = 0; kk < 16; ++kk) {
      double a[4], b[4];
      #pragma unroll
      for (int i = 0; i < 4; ++i) { a[i] = As[kk][4*ty+i]; b[i] = Bs[kk][4*tx+i]; }
      #pragma unroll
      for (int i = 0; i < 4; ++i)
        #pragma unroll
        for (int j = 0; j < 4; ++j) acc[i][j] += a[i]*b[j];
    }
    __syncthreads();
  }
  for (int i = 0; i < 4; ++i) {
    int ii = i0 + 4*ty + i;
    if (ii >= Ml) continue;
    for (int j = 0; j < 4; ++j) {
      int jj = j0 + 4*tx + j;
      if (jj < Nl) C[(size_t)ii*ldc + jj] = acc[i][j];
    }
  }
}

// fpb: fused Newton-Schulz P-build epilogue: C = (15*I - 10*A + 3*(A*B))/8  (A==B==S)
__global__ __launch_bounds__(256) void gemm_nn(const double* __restrict__ A, const double* __restrict__ B,
                                               double* __restrict__ C,
                                               int M, int N, int K, int lda, int ldb, int ldc,
                                               const int* __restrict__ nbp, int cm, int cn, int noff, int ck,
                                               int fpb) {
  int live = nbp ? 16*nbp[0] : 0x7fffffff;
  if (lda < 0) lda = live;
  if (ldb < 0) ldb = live;
  if (ldc < 0) ldc = live;
  int Ml = (cm && live < M) ? live : M;
  int Nl = N;
  if (cn) { int nl = live - noff; Nl = (nl < N) ? nl : N; }
  int Kl = (ck && live < K) ? live : K;
  int i0 = blockIdx.x*64, j0 = blockIdx.y*64;
  if (i0 >= Ml || j0 >= Nl) return;
  __shared__ double As[16][66];
  __shared__ double Bs[16][66];
  int tid = threadIdx.x;
  int tx = tid & 15, ty = tid >> 4;
  double acc[4][4] = {};
  for (int k0 = 0; k0 < Kl; k0 += 16) {
    for (int l = tid; l < 1024; l += 256) {
      int r = l & 15, c = l >> 4;
      As[r][c] = ((i0+c) < Ml && (k0+r) < Kl) ? A[(size_t)(i0+c)*lda + k0+r] : 0.0;
    }
    for (int l = tid; l < 1024; l += 256) {
      int r = l >> 6, c = l & 63;
      Bs[r][c] = ((k0+r) < Kl && (j0+c) < Nl) ? B[(size_t)(k0+r)*ldb + j0+c] : 0.0;
    }
    __syncthreads();
    for (int kk = 0; kk < 16; ++kk) {
      double a[4], b[4];
      #pragma unroll
      for (int i = 0; i < 4; ++i) { a[i] = As[kk][4*ty+i]; b[i] = Bs[kk][4*tx+i]; }
      #pragma unroll
      for (int i = 0; i < 4; ++i)
        #pragma unroll
        for (int j = 0; j < 4; ++j) acc[i][j] += a[i]*b[j];
    }
    __syncthreads();
  }
  for (int i = 0; i < 4; ++i) {
    int ii = i0 + 4*ty + i;
    if (ii >= Ml) continue;
    for (int j = 0; j < 4; ++j) {
      int jj = j0 + 4*tx + j;
      if (jj < Nl) {
        if (fpb) {
          double sv = A[(size_t)ii*lda + jj];
          C[(size_t)ii*ldc + jj] = (15.0*((ii==jj) ? 1.0 : 0.0) - 10.0*sv + 3.0*acc[i][j])*0.125;
        } else {
          C[(size_t)ii*ldc + jj] = acc[i][j];
        }
      }
    }
  }
}

// ---------------- Ptot init: copy live x live of P (ld=cap) into G_g scratch (ld=cap) ------
__global__ void k_ptinit(char* ws, int g, int cap) {
  int live = 16*((const int*)ws)[48+g];
  const double* P = (const double*)(ws + O_P);
  double* A = (double*)(ws + O_G) + goffd(g);
  size_t n = (size_t)live*live;
  for (size_t i = (size_t)blockIdx.x*256 + threadIdx.x; i < n; i += (size_t)gridDim.x*256) {
    int r = (int)(i / live), c = (int)(i % live);
    A[(size_t)r*cap + c] = P[(size_t)r*cap + c];
  }
}

// ---------------- per-band snapshot: Heff copy (G->Jbuf) + RB init (PD->RB) ----------------
__global__ void k_snap(char* ws, int g) {
  const int* desc = (const int*)ws;
  int live = 16*desc[48+g];
  int cap = (g < 8) ? CAPSM : CAP8;
  size_t n1 = (size_t)cap*live;
  size_t n2 = (size_t)live*9;
  const double* Gsrc = (const double*)(ws + O_G) + goffd(g);
  double* Jdst = (double*)(ws + O_J) + goffd(g);
  const double* PD = (const double*)(ws + O_PD) + (size_t)g*1152*9;
  double* RB = (double*)(ws + O_RB) + (size_t)g*1152*9;
  for (size_t i = (size_t)blockIdx.x*256 + threadIdx.x; i < n1 + n2; i += (size_t)gridDim.x*256) {
    if (i < n1) Jdst[i] = Gsrc[i];
    else RB[i - n1] = PD[i - n1];
  }
}

// ---------------- block one-sided Jacobi (R6-exact visit; PER-BAND barriers) ----------------
// Rotation threshold loosened 1e-28 -> 1e-18: skips rotations with |w_pq| < 1e-9*scale
// (eigvec perturbation O(1e-9)); quadratic convergence means local sweeps early-exit
// ~1-2 sweeps sooner and band-done fires earlier. Identity visits remain exact skips.
template<int L>
__device__ __forceinline__ int jacobi_visit(double* __restrict__ G, double* __restrict__ RBg,
    int cap, int ng, int live, int cI, int cJ,
    double* Wab, double* Vs, double* Rls,
    double* cc_, double* ss_, double* crr_, double* srr_,
    int* pp_, int* qq_, int* part_, int* isp_) {
  constexpr int ls = L/2;
  constexpr int P2 = L/2;
  constexpr int ldw = L + 1;
  constexpr int WSZ = 64*65;
  constexpr int AB = L/16;
  const int tid = threadIdx.x;
  const int tx = tid & 15, ty = tid >> 4;
  // ---- gram: W = [G_I|G_J]^T [G_I|G_J]  (Vs aliased as row-chunk staging) ----
  double w[AB][AB];
  #pragma unroll
  for (int a = 0; a < AB; ++a)
    #pragma unroll
    for (int b = 0; b < AB; ++b) w[a][b] = 0.0;
  for (int i0 = 0; i0 < ng; i0 += 64) {
    for (int e = tid; e < 64*L; e += 256) {
      int rw = e & 63, j = e >> 6;
      int cidx = (j < ls) ? (cI + j) : (cJ + (j - ls));
      int i = i0 + rw;
      Vs[rw*ldw + j] = (i < ng && cidx < live) ? G[(size_t)cidx*cap + i] : 0.0;
    }
    __syncthreads();
    #pragma unroll 4
    for (int rw = 0; rw < 64; ++rw) {
      double ra[AB], rb[AB];
      #pragma unroll
      for (int a = 0; a < AB; ++a) ra[a] = Vs[rw*ldw + ty + 16*a];
      #pragma unroll
      for (int b = 0; b < AB; ++b) rb[b] = Vs[rw*ldw + tx + 16*b];
      #pragma unroll
      for (int a = 0; a < AB; ++a)
        #pragma unroll
        for (int b = 0; b < AB; ++b) w[a][b] += ra[a]*rb[b];
    }
    __syncthreads();
  }
  #pragma unroll
  for (int a = 0; a < AB; ++a)
    #pragma unroll
    for (int b = 0; b < AB; ++b)
      Wab[(ty + 16*a)*ldw + tx + 16*b] = w[a][b];
  for (int e = tid; e < L*L; e += 256) {
    int r = e / L, c = e % L;
    Vs[r*ldw + c] = (r == c) ? 1.0 : 0.0;
  }
  __syncthreads();
  // ---- local two-sided Jacobi on W ----
  int cur = 0;
  int blockAny = 0;
  for (int sw = 0; sw < NSWLOC; ++sw) {
    int sweepAny = 0;
    for (int rr2 = 0; rr2 < L-1; ++rr2) {
      int myrot = 0;
      if (tid < P2) {
        int pid = tid, p2, q2;
        if (pid == 0) { p2 = L-1; q2 = rr2; }
        else { p2 = (rr2 + pid) % (L-1); q2 = (rr2 + (L-1) - pid) % (L-1); }
        const double* Wc = Wab + cur*WSZ;
        double wpp = Wc[p2*ldw+p2], wqq = Wc[q2*ldw+q2], wpq = Wc[p2*ldw+q2];
        bool rot = (wpq*wpq > 1e-18*fabs(wpp*wqq) + 1e-280);
        double cr = 1.0, sr = 0.0;
        if (rot) {
          double tau = (wqq - wpp)/(2.0*wpq);
          double tt = (tau >= 0.0 ? 1.0 : -1.0)/(fabs(tau) + sqrt(1.0 + tau*tau));
          cr = 1.0/sqrt(1.0 + tt*tt);
          sr = tt*cr;
        }
        pp_[pid] = p2; qq_[pid] = q2; cc_[pid] = cr; ss_[pid] = sr;
        part_[p2] = q2; part_[q2] = p2;
        isp_[p2] = 1;  isp_[q2] = 0;
        crr_[p2] = cr; crr_[q2] = cr;
        srr_[p2] = sr; srr_[q2] = sr;
        myrot = rot ? 1 : 0;
      }
      int any = __syncthreads_or(myrot);
      if (any) {
        sweepAny = 1;
        const double* Wc = Wab + cur*WSZ;
        double* Wn = Wab + (cur^1)*WSZ;
        #pragma unroll
        for (int jj = 0; jj < (L*P2)/256; ++jj) {
          int e = tid + 256*jj;
          int rw = e / P2, pid = e % P2;
          int p = pp_[pid], q = qq_[pid];
          double cr = cc_[pid], sr = ss_[pid];
          int prn = part_[rw];
          double crR = crr_[rw], srR = srr_[rw];
          int rowIsP = isp_[rw];
          double wrp = Wc[rw*ldw+p],  wrq = Wc[rw*ldw+q];
          double wop = Wc[prn*ldw+p], woq = Wc[prn*ldw+q];
          double rvp, rvq;
          if (rowIsP) { rvp = crR*wrp - srR*wop; rvq = crR*wrq - srR*woq; }
          else        { rvp = srR*wop + crR*wrp; rvq = srR*woq + crR*wrq; }
          Wn[rw*ldw+p] = cr*rvp - sr*rvq;
          Wn[rw*ldw+q] = sr*rvp + cr*rvq;
          double vp = Vs[rw*ldw+p], vq = Vs[rw*ldw+q];
          Vs[rw*ldw+p] = cr*vp - sr*vq;
          Vs[rw*ldw+q] = sr*vp + cr*vq;
        }
        __syncthreads();
        cur ^= 1;
      }
    }
    blockAny |= sweepAny;
    if (!sweepAny) break;
  }
  if (!blockAny) return 0;   // V == I exactly: R and panels unchanged
  // ---- R update: R_panel <- V^T R_panel ----
  for (int e = tid; e < L*9; e += 256) {
    int s = e/9, c = e - 9*s;
    int cidx = (s < ls) ? (cI + s) : (cJ + (s - ls));
    Rls[s*10 + c] = (cidx < live) ? RBg[(size_t)cidx*9 + c] : 0.0;
  }
  __syncthreads();
  for (int e = tid; e < L*9; e += 256) {
    int r = e/9, c = e - 9*r;
    int cidx = (r < ls) ? (cI + r) : (cJ + (r - ls));
    if (cidx < live) {
      double s = 0.0;
      #pragma unroll
      for (int s2 = 0; s2 < L; ++s2) s += Vs[s2*ldw + r]*Rls[s2*10 + c];
      RBg[(size_t)cidx*9 + c] = s;
    }
  }
  // ---- panel update: [G_I|G_J] <- [G_I|G_J] * V ----
  for (int i = tid; i < ng; i += 256) {
    double bg[L];
    #pragma unroll
    for (int rw = 0; rw < L; ++rw) {
      int cidx = (rw < ls) ? (cI + rw) : (cJ + (rw - ls));
      bg[rw] = (cidx < live) ? G[(size_t)cidx*cap + i] : 0.0;
    }
    for (int p = 0; p < L; ++p) {
      double s = 0.0;
      #pragma unroll
      for (int rw = 0; rw < L; ++rw) s += bg[rw]*Vs[rw*ldw + p];
      int cidx = (p < ls) ? (cI + p) : (cJ + (p - ls));
      if (cidx < live) G[(size_t)cidx*cap + i] = s;
    }
  }
  return 1;
}

// per-band sense-reversing barrier (device-scope atomics; blocks co-resident via coop launch)
__device__ __forceinline__ void band_barrier(int* arr, int* gen, int nblk) {
  __syncthreads();
  if (threadIdx.x == 0) {
    __threadfence();   // release: panel/flag writes visible before arrival
    int my = __hip_atomic_load(gen, __ATOMIC_RELAXED, __HIP_MEMORY_SCOPE_AGENT);
    int cnt = __hip_atomic_fetch_add(arr, 1, __ATOMIC_ACQ_REL, __HIP_MEMORY_SCOPE_AGENT);
    if (cnt == nblk - 1) {
      __hip_atomic_store(arr, 0, __ATOMIC_RELAXED, __HIP_MEMORY_SCOPE_AGENT);
      __hip_atomic_fetch_add(gen, 1, __ATOMIC_ACQ_REL, __HIP_MEMORY_SCOPE_AGENT);
    } else {
      while (__hip_atomic_load(gen, __ATOMIC_ACQUIRE, __HIP_MEMORY_SCOPE_AGENT) == my)
        __builtin_amdgcn_s_sleep(2);
    }
    __threadfence();   // acquire: other blocks' writes visible after release
  }
  __syncthreads();
}

__global__ __launch_bounds__(256) void k_bjac(char* ws) {
  const int* desc = (const int*)ws;
  int* sflag = (int*)ws + 7000;          // [NB][SWEEPSB] rotation flags (host-zeroed)
  int* barr  = (int*)ws + 7100;          // [NB] arrival counters (host-zeroed)
  int* bgen  = (int*)ws + 7120;          // [NB] generations (host-zeroed)
  double* Gb = (double*)(ws + O_G);
  __shared__ double Wab_s[2*64*65];
  __shared__ double Vs_s[64*65];
  __shared__ double Rls_s[64*10];
  __shared__ double cc_s[32], ss_s[32], crr_s[64], srr_s[64];
  __shared__ int pp_s[32], qq_s[32], part_s[64], isp_s[64];

  int t = blockIdx.x;
  int g = (t < 160) ? (t/20) : 8;
  int k = (t < 160) ? (t%20) : (t-160);
  int nb16 = desc[48+g];
  int live = 16*nb16;
  int ng = desc[g];
  int ls, nbL;
  if (g < 8) { ls = 16; nbL = nb16; }
  else       { ls = 32; nbL = (nb16 + 1) >> 1; nbL += (nbL & 1); }
  int m = (nbL >= 2) ? nbL - 1 : 1;
  int cap = (g < 8) ? CAPSM : CAP8;
  double* G = Gb + goffd(g);
  double* RBg = (double*)(ws + O_RB) + (size_t)g*1152*9;
  bool bandDone = (nbL < 2);
  int RTg = SWEEPSB*m;

  for (int r = 0; r < RTg; ++r) {
    // band-sweep convergence check (uniform: all band blocks read identical
    // post-barrier sflag state via device-scope RMW) -> whole band exits together
    if (!bandDone && r > 0) {
      int rp = r - 1;
      if ((rp % m) == m-1) {
        int s = rp/m;
        if (atomicOr(&sflag[g*SWEEPSB + s], 0) == 0) bandDone = true;
      }
    }
    if (bandDone) break;
    bool active = (k < nbL/2);
    int cI = 0, cJ = 0;
    if (active) {
      int rr = r % m;
      int I, J;
      if (k == 0) { I = m; J = rr; }
      else { I = (rr + k) % m; J = (rr + m - k) % m; }
      cI = I*ls; cJ = J*ls;
      if (cI >= live && cJ >= live) active = false;
    }
    if (active) {
      int did;
      if (g < 8)
        did = jacobi_visit<32>(G, RBg, cap, ng, live, cI, cJ, Wab_s, Vs_s, Rls_s,
                               cc_s, ss_s, crr_s, srr_s, pp_s, qq_s, part_s, isp_s);
      else
        did = jacobi_visit<64>(G, RBg, cap, ng, live, cI, cJ, Wab_s, Vs_s, Rls_s,
                               cc_s, ss_s, crr_s, srr_s, pp_s, qq_s, part_s, isp_s);
      if (did && threadIdx.x == 0) atomicOr(&sflag[g*SWEEPSB + r/m], 1);
    }
    band_barrier(&barr[g], &bgen[g], 20);
  }
}

// ---------------- eigenvalues: Rayleigh lambda_k = (G_k . HG_k)/(G_k . G_k) ----------------
__global__ void k_eig(char* ws) {
  const int* desc = (const int*)ws;
  double* eva = (double*)(ws + O_EVA);
  int* sid = (int*)(ws + O_SID);
  int wv = (blockIdx.x*blockDim.x + threadIdx.x) >> 6;
  int lane = threadIdx.x & 63;
  if (wv >= SORTN) return;
  if (wv >= NDIM) {
    if (lane == 0) { eva[wv] = 1e300; sid[wv] = wv; }
    return;
  }
  int g = 0;
  while (g < 8 && wv >= desc[16+g+1]) ++g;
  int k = wv - desc[16+g];
  int cap = (g < 8) ? CAPSM : CAP8;
  int ng = desc[g];
  size_t base = goffd(g) + (size_t)k*cap;
  const double* G = (const double*)(ws + O_G) + base;
  const double* HG = (const double*)(ws + O_X1) + base;
  double d1 = 0.0, d2 = 0.0;
  for (int i = lane; i < ng; i += 64) {
    double gv = G[i];
    d1 += gv*HG[i];
    d2 += gv*gv;
  }
  for (int s = 32; s > 0; s >>= 1) {
    d1 += __shfl_xor(d1, s, 64);
    d2 += __shfl_xor(d2, s, 64);
  }
  if (lane == 0) {
    eva[wv] = (d2 > 0.0) ? d1/d2 : 0.0;
    sid[wv] = wv;
  }
}

// ---------------- single-block bitonic sort ----------------
__global__ void k_sort(char* ws) {
  double* key = (double*)(ws + O_EVA);
  int* val = (int*)(ws + O_SID);
  int tid = threadIdx.x;
  for (int size = 2; size <= SORTN; size <<= 1) {
    for (int stride = size >> 1; stride > 0; stride >>= 1) {
      __syncthreads();
      for (int t = tid; t < SORTN/2; t += 1024) {
        int i = 2*t - (t & (stride-1));
        int j = i + stride;
        bool up = ((i & size) == 0);
        double ki = key[i], kj = key[j];
        if ((ki > kj) == up) {
          key[i] = kj; key[j] = ki;
          int v = val[i]; val[i] = val[j]; val[j] = v;
        }
      }
    }
  }
}

// ---------------- final: freq, ir, raman ----------------
__global__ void k_final(char* ws, float* __restrict__ out) {
  int m = blockIdx.x*256 + threadIdx.x;
  if (m >= NOUT) return;
  const int* desc = (const int*)ws;
  const double* eva = (const double*)(ws + O_EVA);
  const int* sid = (const int*)(ws + O_SID);
  int s = m + 6;
  double lam = eva[s];
  int gid = sid[s];
  int g = 0;
  while (g < 8 && gid >= desc[16+g+1]) ++g;
  int k = gid - desc[16+g];
  const double* R = (const double*)(ws + O_RB) + ((size_t)g*1152 + k)*9;
  double q0 = R[0], q1 = R[1], q2 = R[2];
  double ir = 42.2561*(q0*q0 + q1*q1 + q2*q2);
  double xx = R[3], xy = R[4], yy = R[5], xz = R[6], zy = R[7], zz = R[8];
  double alpha = (xx + yy + zz)/3.0;
  double gsq = 0.5*((xx-yy)*(xx-yy) + (yy-zz)*(yy-zz) + (zz-xx)*(zz-xx))
             + 3.0*(xy*xy + xz*xz + zy*zy);
  double raman = (45.0*alpha*alpha + 7.0*gsq)*0.078424;
  double freq = sqrt(fmax(lam, 0.0)*9.375829e28)/(2.0*PI_D)/2.9979245800e10*0.965;
  out[m] = (float)freq;
  out[NOUT + m] = (float)ir;
  out[2*NOUT + m] = (float)raman;
}

__global__ void k_fail(float* out) {
  int i = blockIdx.x*256 + threadIdx.x;
  if (i < 3*NOUT) out[i] = -7777.0f;
}

// ---------------- host ----------------
extern "C" void kernel_launch(void* const* d_in, const int* in_sizes, int n_in,
                              void* d_out, int out_size, void* d_ws, size_t ws_size,
                              hipStream_t stream) {
  const int* z = (const int*)d_in[1];
  const int* ei = (const int*)d_in[2];
  const float* Hi = (const float*)d_in[3];
  const float* Hij = (const float*)d_in[4];
  const float* ded = (const float*)d_in[5];
  const float* dep = (const float*)d_in[6];
  float* out = (float*)d_out;
  char* ws = (char*)d_ws;

  if (ws_size < WS_NEED) {
    k_fail<<<(3*NOUT+255)/256, 256, 0, stream>>>(out);
    return;
  }

  hipMemsetAsync(ws, 0, O_HCOL, stream);
  k_prep<<<1, 256, 0, stream>>>(z, ws);
  k_buildH<<<NA, 128, 0, stream>>>(ei, Hi, Hij, ws);
  k_coeff<<<1, 256, 0, stream>>>(ws);
  k_dt<<<(NDIM+255)/256, 256, 0, stream>>>(ded, dep, ws);

  double* X1 = (double*)(ws + O_X1);    // ortho X, ld=YLD
  double* X2 = (double*)(ws + O_X2);    // cheb output, ld=YLD
  double* Sb = (double*)(ws + O_S);
  double* Pb = (double*)(ws + O_P);
  double* Zb = (double*)(ws + O_S);     // Z chunk aliases S (S dead after NS chain)
  double* Dt = (double*)(ws + O_DT);

  for (int g = 0; g < NB; ++g) {
    int cap = capb(g);
    const int* nbp = ((const int*)(ws)) + 48 + g;
    dim3 gsq((cap+63)/64, (cap+63)/64);
    double* Ag = (double*)(ws + O_G) + goffd(g);   // Ptot ping (dead until Heff)
    double* Bg = (double*)(ws + O_J) + goffd(g);   // Ptot pong (dead until snapshot)

    // ---- column-local Chebyshev -> X2 ----
    k_chebcol<<<dim3((cap+3)/4), 256, 0, stream>>>(ws, g);

    // ---- small-matrix Newton-Schulz on live x live; accumulate Ptot in Ag/Bg ----
    gemm_tn<<<gsq, 256, 0, stream>>>(X2, X2, Sb, cap, cap, NDIM, YLD, YLD, cap, nbp, 1, 1, 0, 0);
    for (int it = 0; it < 5; ++it) {
      gemm_nn<<<gsq, 256, 0, stream>>>(Sb, Sb, Pb, cap, cap, cap, cap, cap, cap, nbp, 1, 1, 0, 1, 1);
      if (it == 0) {
        k_ptinit<<<1024, 256, 0, stream>>>(ws, g, cap);        // Ptot(A) = P1
      } else {
        double* src = (it & 1) ? Ag : Bg;
        double* dst = (it & 1) ? Bg : Ag;
        gemm_nn<<<gsq, 256, 0, stream>>>(src, Pb, dst, cap, cap, cap, cap, cap, cap, nbp, 1, 1, 0, 1, 0);
      }
      if (it < 4) {
        double* Ct = (it & 1) ? Ag : Bg;
        gemm_nn<<<gsq, 256, 0, stream>>>(Sb, Pb, Ct, cap, cap, cap, cap, cap, cap, nbp, 1, 1, 0, 1, 0);
        gemm_nn<<<gsq, 256, 0, stream>>>(Pb, Ct, Sb, cap, cap, cap, cap, cap, cap, nbp, 1, 1, 0, 1, 0);
      }
    }
    // X_ortho = X * Ptot  (Ptot in Ag after it=4)
    gemm_nn<<<dim3((NDIM+63)/64, (cap+63)/64), 256, 0, stream>>>(
        X2, Ag, X1, NDIM, cap, cap, YLD, cap, YLD, nbp, 0, 1, 0, 1, 0);

    // ---- PD_g = X^T Dt ----
    gemm_tn<<<dim3((cap+63)/64, 1), 256, 0, stream>>>(X1, Dt,
        (double*)(ws + O_PD) + (size_t)g*1152*9, cap, 9, NDIM, YLD, 9, 9, nbp, 1, 0, 0, 0);
    // ---- Heff_g = X^T (H X), chunked (overwrites Ag AFTER its last use above) ----
    for (int zc = 0; zc < 2; ++zc) {
      int c0 = zc*ZCHW;
      int cwz = cap - c0; if (cwz > ZCHW) cwz = ZCHW;
      if (cwz <= 0) break;
      dim3 gz(NA, (cwz + 255)/256);
      k_spmm64<<<gz, 256, 0, stream>>>(ws, X1 + c0, Zb, cwz, g, c0, YLD);
      gemm_tn<<<dim3((cap+63)/64, (cwz+63)/64), 256, 0, stream>>>(X1, Zb, Ag + c0,
          cap, cwz, NDIM, YLD, ZCHW, cap, nbp, 1, 1, c0, 0);
    }
    // snapshot Heff -> Jbuf (overwrites Bg scratch), PD -> RB
    k_snap<<<2048, 256, 0, stream>>>(ws, g);
  }

  // joint block one-sided Jacobi on all bands (per-band barriers; bands run concurrently)
  {
    void* args[] = { (void*)&ws };
    hipLaunchCooperativeKernel((void*)k_bjac, dim3(TSLOTS), dim3(256), args, 0, stream);
  }

  // HG_g = G_g(final) x Heff_snapshot  (Rayleigh numerator), per band
  for (int g = 0; g < NB; ++g) {
    int cap = capb(g);
    const int* nbp = ((const int*)(ws)) + 48 + g;
    gemm_nn<<<dim3((cap+63)/64, (cap+63)/64), 256, 0, stream>>>(
        (double*)(ws + O_G) + goffd(g),
        (double*)(ws + O_J) + goffd(g),
        (double*)(ws + O_X1) + goffd(g),
        cap, cap, cap, cap, cap, cap, nbp, 1, 1, 0, 1, 0);
  }

  k_eig<<<(SORTN*64)/256, 256, 0, stream>>>(ws);
  k_sort<<<1, 1024, 0, stream>>>(ws);
  k_final<<<(NOUT+255)/256, 256, 0, stream>>>(ws, out);
}

// Round 13
// 380205.127 us; speedup vs baseline: 1.1138x; 1.0473x over previous
//
#include <hip/hip_runtime.h>
#include <hip/hip_cooperative_groups.h>
#include <math.h>

namespace cg = cooperative_groups;

#define NA      1500
#define NEDGE   48000
#define NDIM    4500
#define NB      9
#define ZCHW    576
#define YLD     1152
#define CAPSM   640
#define CAP8    1152
#define SWEEPSB 8
#define NSWLOC  4
#define TSLOTS  180
#define SORTN   8192
#define COEFLD  864
#define NOUT    4494
#define PI_D    3.14159265358979323846

// Chebyshev filter degrees
static const int H_DEG[NB] = {24, 48, 96, 160, 320, 320, 336, 336, 272};
__device__ __constant__ int d_DEG[NB] = {24, 48, 96, 160, 320, 320, 336, 336, 272};
__device__ __constant__ double d_MASS[10] = {1.008,4.003,6.941,9.012,10.811,12.011,14.007,15.999,18.998,20.18};
__device__ __constant__ double d_BLO[NB] = {31.04695, 9.84715, 6.37590, 5.08655, 4.39385, 3.86620, 3.34740, 2.87855, -1.0e9};
__device__ __constant__ double d_BHI[NB] = {1.0e9, 31.04695, 9.84715, 6.37590, 5.08655, 4.39385, 3.86620, 3.34740, 2.87855};

// ---------------- workspace layout (bytes) ----------------
constexpr size_t O_DESC = 0;
constexpr size_t O_WM   = 32768;
constexpr size_t O_MINV = O_WM + 12288;
constexpr size_t O_GER  = O_MINV + 12288;
constexpr size_t O_CH   = O_GER + 24576;
constexpr size_t O_COEF = O_CH + 256;
constexpr size_t O_DT   = O_COEF + (size_t)NB*COEFLD*8;
constexpr size_t O_PD   = O_DT + (size_t)NDIM*9*8;
constexpr size_t O_RB   = O_PD + (size_t)NB*1152*9*8;
constexpr size_t O_EVA  = O_RB + (size_t)NB*1152*9*8;
constexpr size_t O_SID  = O_EVA + (size_t)SORTN*8;
constexpr size_t O_HCOL = O_SID + (size_t)SORTN*4;
constexpr size_t O_HV64 = O_HCOL + (size_t)NA*65*4;      // f64[1500*65*9] (spmm64)
constexpr size_t O_HV32 = O_HV64 + (size_t)NA*65*9*8;    // (reserved; legacy spacing)
constexpr size_t O_Y    = O_HV32 + (size_t)NA*65*12*4;   // hosts HA/HB/HC f32 transposed H
constexpr size_t O_HA   = O_Y;                           // float4[65*1500]  h[0..3]
constexpr size_t O_HB   = O_HA + (size_t)65*NA*16;       // float4[65*1500]  h[4..7]
constexpr size_t O_HC   = O_HB + (size_t)65*NA*16;       // float [65*1500]  h[8]
constexpr size_t O_X1   = O_Y + (size_t)NDIM*YLD*4;      // ortho X (ld=YLD); HG scratch after bjac
constexpr size_t O_X2   = O_X1 + (size_t)NDIM*YLD*8;     // cheb output (ld=YLD)
constexpr size_t O_S    = O_X2 + (size_t)NDIM*YLD*8;     // S; Z chunk aliases S after NS
constexpr size_t O_P    = O_S + (size_t)CAP8*CAP8*8;     // P
constexpr size_t O_G    = O_P + (size_t)CAP8*CAP8*8;     // Heff; during NS: Ptot ping scratch
constexpr size_t GTOT   = (size_t)8*CAPSM*CAPSM + (size_t)CAP8*CAP8;
constexpr size_t O_J    = O_G + GTOT*8;                  // Heff snapshot; during NS: Ptot pong
constexpr size_t WS_NEED = O_J + GTOT*8;                 // ~213 MB

__host__ __device__ inline size_t goffd(int g){ return (g < 8) ? (size_t)g*CAPSM*CAPSM : (size_t)8*CAPSM*CAPSM; }
__host__ inline int capb(int g){ return (g < 8) ? CAPSM : CAP8; }

// ---------------- prep ----------------
__global__ void k_prep(const int* __restrict__ z, char* ws) {
  int* desc = (int*)ws;
  double* wm = (double*)(ws + O_WM);
  double* minv = (double*)(ws + O_MINV);
  __shared__ int zb[NA];
  __shared__ int cnt[NB];
  int tid = threadIdx.x;
  if (tid < NB) cnt[tid] = 0;
  __syncthreads();
  for (int a = tid; a < NA; a += blockDim.x) {
    int zz = z[a];
    int b = (zz >= 8) ? 8 : zz;
    zb[a] = b;
    atomicAdd(&cnt[b], 1);
    double m = d_MASS[zz];
    wm[a] = 1.0/sqrt(m);
    minv[a] = 1.0/m;
  }
  __syncthreads();
  if (tid == 0) {
    int off = 0;
    for (int g = 0; g < NB; ++g) {
      desc[16+g] = 3*off;
      int ng = 3*cnt[g];
      int cap = (g < 8) ? CAPSM : CAP8;
      ng = (ng > cap) ? cap : ng;
      desc[g] = ng;
      desc[32+g] = ng + (ng & 1);
      int nb = (ng + 15)/16;
      if (nb & 1) nb++;
      desc[48+g] = nb;
      off += cnt[g];
    }
    desc[16+NB] = 3*off;
  }
  __syncthreads();
  for (int a = tid; a < NA; a += blockDim.x) {
    int b = zb[a]; int r = 0;
    for (int x = 0; x < a; ++x) r += (zb[x] == b) ? 1 : 0;
    if (r < 512) desc[64 + b*512 + r] = a;
    desc[5120 + a] = (r & 0xffff) | (b << 16);   // atom -> (rank, band)
  }
}

// ---------------- build sparse mass-weighted symmetrized H ----------------
__global__ void k_buildH(const int* __restrict__ ei, const float* __restrict__ Hi,
                         const float* __restrict__ Hij, char* ws) {
  int p = blockIdx.x, t = threadIdx.x;
  const double* wm = (const double*)(ws + O_WM);
  const double* minv = (const double*)(ws + O_MINV);
  int* hcol = (int*)(ws + O_HCOL);
  double* hv = (double*)(ws + O_HV64);
  float4* HAp = (float4*)(ws + O_HA);
  float4* HBp = (float4*)(ws + O_HB);
  float*  HCp = (float*)(ws + O_HC);
  __shared__ double rowabs[3][72];
  __shared__ double dcen[3];
  double v[9];
  int q = -1;
  if (t == 0) {
    q = p;
    double mi = minv[p];
    for (int a = 0; a < 3; ++a)
      for (int b = 0; b < 3; ++b)
        v[3*a+b] = 0.5*((double)Hi[9*p+3*a+b] + (double)Hi[9*p+3*b+a])*mi;
    for (int a = 0; a < 3; ++a) dcen[a] = v[3*a+a];
  } else if (t <= 32) {
    int off = t;
    int e = 32*p + off - 1;
    q = ei[e];
    double ww = 0.5*wm[p]*wm[q];
    for (int a = 0; a < 3; ++a)
      for (int b = 0; b < 3; ++b)
        v[3*a+b] = ww*(double)Hij[9*e+3*a+b];
  } else if (t <= 64) {
    int off = t - 32;
    int qr = (p + NA - off) % NA;
    int e = 32*qr + off - 1;
    q = ei[NEDGE + e];
    double ww = 0.5*wm[p]*wm[q];
    for (int a = 0; a < 3; ++a)
      for (int b = 0; b < 3; ++b)
        v[3*a+b] = ww*(double)Hij[9*e+3*b+a];
  }
  if (t < 65) {
    hcol[p*65+t] = q;
    for (int k = 0; k < 9; ++k)
      hv[((size_t)p*65+t)*9+k] = v[k];
    HAp[(size_t)t*NA + p] = make_float4((float)v[0],(float)v[1],(float)v[2],(float)v[3]);
    HBp[(size_t)t*NA + p] = make_float4((float)v[4],(float)v[5],(float)v[6],(float)v[7]);
    HCp[(size_t)t*NA + p] = (float)v[8];
    for (int a = 0; a < 3; ++a)
      rowabs[a][t] = fabs(v[3*a]) + fabs(v[3*a+1]) + fabs(v[3*a+2]);
  }
  __syncthreads();
  if (t == 0) {
    double hi = -1e300, lo = 1e300;
    for (int a = 0; a < 3; ++a) {
      double s = 0.0;
      for (int k = 0; k < 65; ++k) s += rowabs[a][k];
      double rad = s - fabs(dcen[a]);
      hi = fmax(hi, dcen[a] + rad);
      lo = fmin(lo, dcen[a] - rad);
    }
    double* ger = (double*)(ws + O_GER);
    ger[2*p] = hi; ger[2*p+1] = lo;
  }
}

// ---------------- spectrum bounds + Jackson-Chebyshev coefficients ----------------
__global__ void k_coeff(char* ws) {
  __shared__ double shi[256], slo[256];
  int tid = threadIdx.x;
  const double* ger = (const double*)(ws + O_GER);
  double hi = -1e300, lo = 1e300;
  for (int i = tid; i < NA; i += 256) { hi = fmax(hi, ger[2*i]); lo = fmin(lo, ger[2*i+1]); }
  shi[tid] = hi; slo[tid] = lo;
  __syncthreads();
  for (int s = 128; s > 0; s >>= 1) {
    if (tid < s) { shi[tid] = fmax(shi[tid], shi[tid+s]); slo[tid] = fmin(slo[tid], slo[tid+s]); }
    __syncthreads();
  }
  double* ch = (double*)(ws + O_CH);
  if (tid == 0) {
    double c = 0.5*(shi[0]+slo[0]);
    double h = 0.5*(shi[0]-slo[0])*1.002;
    ch[0] = c; ch[1] = h;
  }
  __syncthreads();
  double c = ch[0], h = ch[1];
  double* coef = (double*)(ws + O_COEF);
  for (int g = 0; g < NB; ++g) {
    int d = d_DEG[g];
    double xlo = fmin(1.0, fmax(-1.0, (d_BLO[g]-c)/h));
    double xhi = fmin(1.0, fmax(-1.0, (d_BHI[g]-c)/h));
    double f1 = acos(xlo), f2 = acos(xhi);
    double alp = PI_D/(double)(d+1);
    double ct = cos(alp)/sin(alp);
    for (int k = tid; k <= d; k += 256) {
      double ck = (k == 0) ? (f1-f2)/PI_D : 2.0*(sin(k*f1)-sin(k*f2))/(k*PI_D);
      double jk = ((double)(d+1-k)*cos(k*alp) + sin(k*alp)*ct)/(double)(d+1);
      coef[g*COEFLD+k] = ck*jk;
    }
  }
}

// ---------------- mass-weighted dipole/polar matrix Dt[4500][9] ----------------
__global__ void k_dt(const float* __restrict__ ded, const float* __restrict__ dep, char* ws) {
  int row = blockIdx.x*256 + threadIdx.x;
  if (row >= NDIM) return;
  int p = row/3, a = row%3;
  const double* wm = (const double*)(ws + O_WM);
  double w = wm[p];
  double* dt = (double*)(ws + O_DT) + (size_t)row*9;
  for (int cI = 0; cI < 3; ++cI) dt[cI] = w*(double)ded[9*p+3*a+cI];
  for (int cI = 0; cI < 6; ++cI) dt[3+cI] = w*(double)dep[18*p+6*a+cI];
}

// ================= column-local Chebyshev (ZERO per-step boundaries) =================
#define AP(r) ((r) + ((r)>>4))   // LDS pad

__device__ __forceinline__ float4 f4m3(float4 acc, float s0, const float4 v0,
                                       float s1, const float4 v1, float s2, const float4 v2) {
  acc.x += s0*v0.x + s1*v1.x + s2*v2.x;
  acc.y += s0*v0.y + s1*v1.y + s2*v2.y;
  acc.z += s0*v0.z + s1*v1.z + s2*v2.z;
  acc.w += s0*v0.w + s1*v1.w + s2*v2.w;
  return acc;
}

__global__ __launch_bounds__(256, 2) void k_chebcol(char* ws, int g) {
  const int* desc = (const int*)ws;
  const int ng = desc[g];
  const int live = 16*desc[48+g];
  const int c0 = 4*(int)blockIdx.x;
  if (c0 >= live) return;
  const int deg = d_DEG[g];
  const int tid = threadIdx.x;
  __shared__ float4 Asb[AP(4500)];
  const float4* HA = (const float4*)(ws + O_HA);
  const float4* HB = (const float4*)(ws + O_HB);
  const float*  HC = (const float*)(ws + O_HC);
  const double* ch = (const double*)(ws + O_CH);
  const float cc = (float)ch[0];
  const float hinv = (float)(1.0/ch[1]);
  const double* coefd = (const double*)(ws + O_COEF) + (size_t)g*COEFLD;
  const float g0 = (float)coefd[0];

  float4 Bv[18];
  float4 Yv[18];

  #pragma unroll
  for (int i = 0; i < 6; ++i) {
    int atom = tid + 256*i;
    if (atom < NA) {
      int rb = desc[5120 + atom];
      int arank = rb & 0xffff;
      int aband = rb >> 16;
      int jc0 = 3*arank;
      #pragma unroll
      for (int a = 0; a < 3; ++a) {
        float4 t0;
        int jc = jc0 + a;
        bool lv = (aband == g) && (jc < ng);
        t0.x = (lv && jc == c0+0) ? 1.0f : 0.0f;
        t0.y = (lv && jc == c0+1) ? 1.0f : 0.0f;
        t0.z = (lv && jc == c0+2) ? 1.0f : 0.0f;
        t0.w = (lv && jc == c0+3) ? 1.0f : 0.0f;
        Asb[AP(3*atom+a)] = t0;
        Yv[3*i+a] = make_float4(g0*t0.x, g0*t0.y, g0*t0.z, g0*t0.w);
        Bv[3*i+a] = make_float4(0.0f, 0.0f, 0.0f, 0.0f);
      }
    }
  }
  __syncthreads();

  for (int k = 1; k <= deg; ++k) {
    const float gam = (float)coefd[k];
    const bool first = (k == 1);
    #pragma unroll
    for (int i = 0; i < 6; ++i) {
      int atom = tid + 256*i;
      if (atom < NA) {
        float4 acc0 = make_float4(0,0,0,0), acc1 = acc0, acc2 = acc0;
        float4 xd0 = acc0, xd1 = acc0, xd2 = acc0;
        #pragma unroll 5
        for (int du = -32; du <= 32; ++du) {
          int q = atom + du;
          if (q < 0) q += NA; else if (q >= NA) q -= NA;
          int t = (du == 0) ? 0 : ((du > 0) ? du : 32 - du);
          size_t hidx = (size_t)t*NA + atom;
          float4 ha = HA[hidx];
          float4 hb = HB[hidx];
          float  hc = HC[hidx];
          int r = 3*q;
          float4 r0 = Asb[AP(r)];
          float4 r1 = Asb[AP(r+1)];
          float4 r2 = Asb[AP(r+2)];
          if (du == 0) { xd0 = r0; xd1 = r1; xd2 = r2; }
          acc0 = f4m3(acc0, ha.x, r0, ha.y, r1, ha.z, r2);
          acc1 = f4m3(acc1, ha.w, r0, hb.x, r1, hb.y, r2);
          acc2 = f4m3(acc2, hb.z, r0, hb.w, r1, hc,  r2);
        }
        #pragma unroll
        for (int a = 0; a < 3; ++a) {
          float4 accv = (a == 0) ? acc0 : ((a == 1) ? acc1 : acc2);
          float4 xdv  = (a == 0) ? xd0  : ((a == 1) ? xd1  : xd2);
          int bi = 3*i + a;
          float4 u, tn;
          u.x = (accv.x - cc*xdv.x)*hinv;
          u.y = (accv.y - cc*xdv.y)*hinv;
          u.z = (accv.z - cc*xdv.z)*hinv;
          u.w = (accv.w - cc*xdv.w)*hinv;
          tn.x = first ? u.x : (2.0f*u.x - Bv[bi].x);
          tn.y = first ? u.y : (2.0f*u.y - Bv[bi].y);
          tn.z = first ? u.z : (2.0f*u.z - Bv[bi].z);
          tn.w = first ? u.w : (2.0f*u.w - Bv[bi].w);
          Yv[bi].x += gam*tn.x;
          Yv[bi].y += gam*tn.y;
          Yv[bi].z += gam*tn.z;
          Yv[bi].w += gam*tn.w;
          Bv[bi] = tn;
        }
      }
    }
    __syncthreads();
    #pragma unroll
    for (int i = 0; i < 6; ++i) {
      int atom = tid + 256*i;
      if (atom < NA) {
        #pragma unroll
        for (int a = 0; a < 3; ++a) {
          int r = AP(3*atom+a);
          int bi = 3*i + a;
          float4 tmp = Asb[r];
          Asb[r] = Bv[bi];
          Bv[bi] = tmp;
        }
      }
    }
    __syncthreads();
  }

  double* X2 = (double*)(ws + O_X2);
  #pragma unroll
  for (int i = 0; i < 6; ++i) {
    int atom = tid + 256*i;
    if (atom < NA) {
      #pragma unroll
      for (int a = 0; a < 3; ++a) {
        int row = 3*atom + a;
        double* xr = X2 + (size_t)row*YLD;
        float4 y = Yv[3*i+a];
        if (c0+0 < live) xr[c0+0] = (c0+0 < ng) ? (double)y.x : 0.0;
        if (c0+1 < live) xr[c0+1] = (c0+1 < ng) ? (double)y.y : 0.0;
        if (c0+2 < live) xr[c0+2] = (c0+2 < ng) ? (double)y.z : 0.0;
        if (c0+3 < live) xr[c0+3] = (c0+3 < ng) ? (double)y.w : 0.0;
      }
    }
  }
}

// ---------------- f64 SpMM: Z = H * X(cols c0..c0+cw), clamped to live band width ------
__global__ __launch_bounds__(256) void k_spmm64(char* ws, const double* __restrict__ X,
                                                double* __restrict__ Z, int cw, int g, int cpos,
                                                int xld) {
  int live = 16*((const int*)ws)[48+g];
  if (xld < 0) xld = live;
  int cb = blockIdx.y*256;
  if (cpos + cb >= live) return;
  __shared__ double sval[585];
  __shared__ int scol[65];
  int p = blockIdx.x;
  const double* hv = (const double*)(ws + O_HV64) + (size_t)p*585;
  const int* hcol = (const int*)(ws + O_HCOL) + p*65;
  for (int l = threadIdx.x; l < 585; l += 256) sval[l] = hv[l];
  if (threadIdx.x < 65) scol[threadIdx.x] = hcol[threadIdx.x];
  __syncthreads();
  int col = cb + threadIdx.x;
  if (col >= cw || cpos + col >= live) return;
  double a0 = 0.0, a1 = 0.0, a2 = 0.0;
  for (int t = 0; t < 65; ++t) {
    int q = scol[t];
    const double* xb = X + (size_t)(3*q)*xld + col;
    double x0 = xb[0], x1 = xb[xld], x2 = xb[2*xld];
    const double* v = sval + t*9;
    a0 += v[0]*x0 + v[1]*x1 + v[2]*x2;
    a1 += v[3]*x0 + v[4]*x1 + v[5]*x2;
    a2 += v[6]*x0 + v[7]*x1 + v[8]*x2;
  }
  Z[(size_t)(3*p+0)*ZCHW + col] = a0;
  Z[(size_t)(3*p+1)*ZCHW + col] = a1;
  Z[(size_t)(3*p+2)*ZCHW + col] = a2;
}

// ---------------- f64 GEMMs (loads & writes clamped to Ml/Nl/Kl) ----------------
__global__ __launch_bounds__(256) void gemm_tn(const double* __restrict__ A, const double* __restrict__ B,
                                               double* __restrict__ C,
                                               int M, int N, int K, int lda, int ldb, int ldc,
                                               const int* __restrict__ nbp, int cm, int cn, int noff, int ck) {
  int live = nbp ? 16*nbp[0] : 0x7fffffff;
  if (lda < 0) lda = live;
  if (ldb < 0) ldb = live;
  if (ldc < 0) ldc = live;
  int Ml = (cm && live < M) ? live : M;
  int Nl = N;
  if (cn) { int nl = live - noff; Nl = (nl < N) ? nl : N; }
  int Kl = (ck && live < K) ? live : K;
  int i0 = blockIdx.x*64, j0 = blockIdx.y*64;
  if (i0 >= Ml || j0 >= Nl) return;
  __shared__ double As[16][66];
  __shared__ double Bs[16][66];
  int tid = threadIdx.x;
  int tx = tid & 15, ty = tid >> 4;
  double acc[4][4] = {};
  for (int k0 = 0; k0 < Kl; k0 += 16) {
    for (int l = tid; l < 1024; l += 256) {
      int r = l >> 6, c = l & 63;
      int kk = k0 + r;
      As[r][c] = (kk < Kl && i0+c < Ml) ? A[(size_t)kk*lda + i0+c] : 0.0;
    }
    for (int l = tid; l < 1024; l += 256) {
      int r = l >> 6, c = l & 63;
      int kk = k0 + r;
      Bs[r][c] = (kk < Kl && j0+c < Nl) ? B[(size_t)kk*ldb + j0+c] : 0.0;
    }
    __syncthreads();
    for (int kk = 0; kk < 16; ++kk) {
      double a[4], b[4];
      #pragma unroll
      for (int i = 0; i < 4; ++i) { a[i] = As[kk][4*ty+i]; b[i] = Bs[kk][4*tx+i]; }
      #pragma unroll
      for (int i = 0; i < 4; ++i)
        #pragma unroll
        for (int j = 0; j < 4; ++j) acc[i][j] += a[i]*b[j];
    }
    __syncthreads();
  }
  for (int i = 0; i < 4; ++i) {
    int ii = i0 + 4*ty + i;
    if (ii >= Ml) continue;
    for (int j = 0; j < 4; ++j) {
      int jj = j0 + 4*tx + j;
      if (jj < Nl) C[(size_t)ii*ldc + jj] = acc[i][j];
    }
  }
}

// fpb: fused Newton-Schulz P-build epilogue: C = (15*I - 10*A + 3*(A*B))/8  (A==B==S)
__global__ __launch_bounds__(256) void gemm_nn(const double* __restrict__ A, const double* __restrict__ B,
                                               double* __restrict__ C,
                                               int M, int N, int K, int lda, int ldb, int ldc,
                                               const int* __restrict__ nbp, int cm, int cn, int noff, int ck,
                                               int fpb) {
  int live = nbp ? 16*nbp[0] : 0x7fffffff;
  if (lda < 0) lda = live;
  if (ldb < 0) ldb = live;
  if (ldc < 0) ldc = live;
  int Ml = (cm && live < M) ? live : M;
  int Nl = N;
  if (cn) { int nl = live - noff; Nl = (nl < N) ? nl : N; }
  int Kl = (ck && live < K) ? live : K;
  int i0 = blockIdx.x*64, j0 = blockIdx.y*64;
  if (i0 >= Ml || j0 >= Nl) return;
  __shared__ double As[16][66];
  __shared__ double Bs[16][66];
  int tid = threadIdx.x;
  int tx = tid & 15, ty = tid >> 4;
  double acc[4][4] = {};
  for (int k0 = 0; k0 < Kl; k0 += 16) {
    for (int l = tid; l < 1024; l += 256) {
      int r = l & 15, c = l >> 4;
      As[r][c] = ((i0+c) < Ml && (k0+r) < Kl) ? A[(size_t)(i0+c)*lda + k0+r] : 0.0;
    }
    for (int l = tid; l < 1024; l += 256) {
      int r = l >> 6, c = l & 63;
      Bs[r][c] = ((k0+r) < Kl && (j0+c) < Nl) ? B[(size_t)(k0+r)*ldb + j0+c] : 0.0;
    }
    __syncthreads();
    for (int kk = 0; kk < 16; ++kk) {
      double a[4], b[4];
      #pragma unroll
      for (int i = 0; i < 4; ++i) { a[i] = As[kk][4*ty+i]; b[i] = Bs[kk][4*tx+i]; }
      #pragma unroll
      for (int i = 0; i < 4; ++i)
        #pragma unroll
        for (int j = 0; j < 4; ++j) acc[i][j] += a[i]*b[j];
    }
    __syncthreads();
  }
  for (int i = 0; i < 4; ++i) {
    int ii = i0 + 4*ty + i;
    if (ii >= Ml) continue;
    for (int j = 0; j < 4; ++j) {
      int jj = j0 + 4*tx + j;
      if (jj < Nl) {
        if (fpb) {
          double sv = A[(size_t)ii*lda + jj];
          C[(size_t)ii*ldc + jj] = (15.0*((ii==jj) ? 1.0 : 0.0) - 10.0*sv + 3.0*acc[i][j])*0.125;
        } else {
          C[(size_t)ii*ldc + jj] = acc[i][j];
        }
      }
    }
  }
}

// ---------------- Ptot init: copy live x live of P (ld=cap) into G_g scratch (ld=cap) ------
__global__ void k_ptinit(char* ws, int g, int cap) {
  int live = 16*((const int*)ws)[48+g];
  const double* P = (const double*)(ws + O_P);
  double* A = (double*)(ws + O_G) + goffd(g);
  size_t n = (size_t)live*live;
  for (size_t i = (size_t)blockIdx.x*256 + threadIdx.x; i < n; i += (size_t)gridDim.x*256) {
    int r = (int)(i / live), c = (int)(i % live);
    A[(size_t)r*cap + c] = P[(size_t)r*cap + c];
  }
}

// ---------------- per-band snapshot: Heff copy (G->Jbuf) + RB init (PD->RB) ----------------
__global__ void k_snap(char* ws, int g) {
  const int* desc = (const int*)ws;
  int live = 16*desc[48+g];
  int cap = (g < 8) ? CAPSM : CAP8;
  size_t n1 = (size_t)cap*live;
  size_t n2 = (size_t)live*9;
  const double* Gsrc = (const double*)(ws + O_G) + goffd(g);
  double* Jdst = (double*)(ws + O_J) + goffd(g);
  const double* PD = (const double*)(ws + O_PD) + (size_t)g*1152*9;
  double* RB = (double*)(ws + O_RB) + (size_t)g*1152*9;
  for (size_t i = (size_t)blockIdx.x*256 + threadIdx.x; i < n1 + n2; i += (size_t)gridDim.x*256) {
    if (i < n1) Jdst[i] = Gsrc[i];
    else RB[i - n1] = PD[i - n1];
  }
}

// ---------------- block one-sided Jacobi (R6-exact visit; PER-BAND barriers) ----------------
// NSWLOC=4 (block-Jacobi needs only partial local convergence per visit) and rotation
// threshold 1e-14 (skip |w_pq| < 1e-7*scale; eigvec perturbation O(1e-7)). Convergence
// safety net unchanged: SWEEPSB global sweeps + per-sweep rotation flags + early exits.
template<int L>
__device__ __forceinline__ int jacobi_visit(double* __restrict__ G, double* __restrict__ RBg,
    int cap, int ng, int live, int cI, int cJ,
    double* Wab, double* Vs, double* Rls,
    double* cc_, double* ss_, double* crr_, double* srr_,
    int* pp_, int* qq_, int* part_, int* isp_) {
  constexpr int ls = L/2;
  constexpr int P2 = L/2;
  constexpr int ldw = L + 1;
  constexpr int WSZ = 64*65;
  constexpr int AB = L/16;
  const int tid = threadIdx.x;
  const int tx = tid & 15, ty = tid >> 4;
  // ---- gram: W = [G_I|G_J]^T [G_I|G_J]  (Vs aliased as row-chunk staging) ----
  double w[AB][AB];
  #pragma unroll
  for (int a = 0; a < AB; ++a)
    #pragma unroll
    for (int b = 0; b < AB; ++b) w[a][b] = 0.0;
  for (int i0 = 0; i0 < ng; i0 += 64) {
    for (int e = tid; e < 64*L; e += 256) {
      int rw = e & 63, j = e >> 6;
      int cidx = (j < ls) ? (cI + j) : (cJ + (j - ls));
      int i = i0 + rw;
      Vs[rw*ldw + j] = (i < ng && cidx < live) ? G[(size_t)cidx*cap + i] : 0.0;
    }
    __syncthreads();
    #pragma unroll 4
    for (int rw = 0; rw < 64; ++rw) {
      double ra[AB], rb[AB];
      #pragma unroll
      for (int a = 0; a < AB; ++a) ra[a] = Vs[rw*ldw + ty + 16*a];
      #pragma unroll
      for (int b = 0; b < AB; ++b) rb[b] = Vs[rw*ldw + tx + 16*b];
      #pragma unroll
      for (int a = 0; a < AB; ++a)
        #pragma unroll
        for (int b = 0; b < AB; ++b) w[a][b] += ra[a]*rb[b];
    }
    __syncthreads();
  }
  #pragma unroll
  for (int a = 0; a < AB; ++a)
    #pragma unroll
    for (int b = 0; b < AB; ++b)
      Wab[(ty + 16*a)*ldw + tx + 16*b] = w[a][b];
  for (int e = tid; e < L*L; e += 256) {
    int r = e / L, c = e % L;
    Vs[r*ldw + c] = (r == c) ? 1.0 : 0.0;
  }
  __syncthreads();
  // ---- local two-sided Jacobi on W ----
  int cur = 0;
  int blockAny = 0;
  for (int sw = 0; sw < NSWLOC; ++sw) {
    int sweepAny = 0;
    for (int rr2 = 0; rr2 < L-1; ++rr2) {
      int myrot = 0;
      if (tid < P2) {
        int pid = tid, p2, q2;
        if (pid == 0) { p2 = L-1; q2 = rr2; }
        else { p2 = (rr2 + pid) % (L-1); q2 = (rr2 + (L-1) - pid) % (L-1); }
        const double* Wc = Wab + cur*WSZ;
        double wpp = Wc[p2*ldw+p2], wqq = Wc[q2*ldw+q2], wpq = Wc[p2*ldw+q2];
        bool rot = (wpq*wpq > 1e-14*fabs(wpp*wqq) + 1e-280);
        double cr = 1.0, sr = 0.0;
        if (rot) {
          double tau = (wqq - wpp)/(2.0*wpq);
          double tt = (tau >= 0.0 ? 1.0 : -1.0)/(fabs(tau) + sqrt(1.0 + tau*tau));
          cr = 1.0/sqrt(1.0 + tt*tt);
          sr = tt*cr;
        }
        pp_[pid] = p2; qq_[pid] = q2; cc_[pid] = cr; ss_[pid] = sr;
        part_[p2] = q2; part_[q2] = p2;
        isp_[p2] = 1;  isp_[q2] = 0;
        crr_[p2] = cr; crr_[q2] = cr;
        srr_[p2] = sr; srr_[q2] = sr;
        myrot = rot ? 1 : 0;
      }
      int any = __syncthreads_or(myrot);
      if (any) {
        sweepAny = 1;
        const double* Wc = Wab + cur*WSZ;
        double* Wn = Wab + (cur^1)*WSZ;
        #pragma unroll
        for (int jj = 0; jj < (L*P2)/256; ++jj) {
          int e = tid + 256*jj;
          int rw = e / P2, pid = e % P2;
          int p = pp_[pid], q = qq_[pid];
          double cr = cc_[pid], sr = ss_[pid];
          int prn = part_[rw];
          double crR = crr_[rw], srR = srr_[rw];
          int rowIsP = isp_[rw];
          double wrp = Wc[rw*ldw+p],  wrq = Wc[rw*ldw+q];
          double wop = Wc[prn*ldw+p], woq = Wc[prn*ldw+q];
          double rvp, rvq;
          if (rowIsP) { rvp = crR*wrp - srR*wop; rvq = crR*wrq - srR*woq; }
          else        { rvp = srR*wop + crR*wrp; rvq = srR*woq + crR*wrq; }
          Wn[rw*ldw+p] = cr*rvp - sr*rvq;
          Wn[rw*ldw+q] = sr*rvp + cr*rvq;
          double vp = Vs[rw*ldw+p], vq = Vs[rw*ldw+q];
          Vs[rw*ldw+p] = cr*vp - sr*vq;
          Vs[rw*ldw+q] = sr*vp + cr*vq;
        }
        __syncthreads();
        cur ^= 1;
      }
    }
    blockAny |= sweepAny;
    if (!sweepAny) break;
  }
  if (!blockAny) return 0;   // V == I exactly: R and panels unchanged
  // ---- R update: R_panel <- V^T R_panel ----
  for (int e = tid; e < L*9; e += 256) {
    int s = e/9, c = e - 9*s;
    int cidx = (s < ls) ? (cI + s) : (cJ + (s - ls));
    Rls[s*10 + c] = (cidx < live) ? RBg[(size_t)cidx*9 + c] : 0.0;
  }
  __syncthreads();
  for (int e = tid; e < L*9; e += 256) {
    int r = e/9, c = e - 9*r;
    int cidx = (r < ls) ? (cI + r) : (cJ + (r - ls));
    if (cidx < live) {
      double s = 0.0;
      #pragma unroll
      for (int s2 = 0; s2 < L; ++s2) s += Vs[s2*ldw + r]*Rls[s2*10 + c];
      RBg[(size_t)cidx*9 + c] = s;
    }
  }
  // ---- panel update: [G_I|G_J] <- [G_I|G_J] * V ----
  for (int i = tid; i < ng; i += 256) {
    double bg[L];
    #pragma unroll
    for (int rw = 0; rw < L; ++rw) {
      int cidx = (rw < ls) ? (cI + rw) : (cJ + (rw - ls));
      bg[rw] = (cidx < live) ? G[(size_t)cidx*cap + i] : 0.0;
    }
    for (int p = 0; p < L; ++p) {
      double s = 0.0;
      #pragma unroll
      for (int rw = 0; rw < L; ++rw) s += bg[rw]*Vs[rw*ldw + p];
      int cidx = (p < ls) ? (cI + p) : (cJ + (p - ls));
      if (cidx < live) G[(size_t)cidx*cap + i] = s;
    }
  }
  return 1;
}

// per-band sense-reversing barrier (device-scope atomics; blocks co-resident via coop launch)
__device__ __forceinline__ void band_barrier(int* arr, int* gen, int nblk) {
  __syncthreads();
  if (threadIdx.x == 0) {
    __threadfence();   // release: panel/flag writes visible before arrival
    int my = __hip_atomic_load(gen, __ATOMIC_RELAXED, __HIP_MEMORY_SCOPE_AGENT);
    int cnt = __hip_atomic_fetch_add(arr, 1, __ATOMIC_ACQ_REL, __HIP_MEMORY_SCOPE_AGENT);
    if (cnt == nblk - 1) {
      __hip_atomic_store(arr, 0, __ATOMIC_RELAXED, __HIP_MEMORY_SCOPE_AGENT);
      __hip_atomic_fetch_add(gen, 1, __ATOMIC_ACQ_REL, __HIP_MEMORY_SCOPE_AGENT);
    } else {
      while (__hip_atomic_load(gen, __ATOMIC_ACQUIRE, __HIP_MEMORY_SCOPE_AGENT) == my)
        __builtin_amdgcn_s_sleep(2);
    }
    __threadfence();   // acquire: other blocks' writes visible after release
  }
  __syncthreads();
}

__global__ __launch_bounds__(256) void k_bjac(char* ws) {
  const int* desc = (const int*)ws;
  int* sflag = (int*)ws + 7000;          // [NB][SWEEPSB] rotation flags (host-zeroed)
  int* barr  = (int*)ws + 7100;          // [NB] arrival counters (host-zeroed)
  int* bgen  = (int*)ws + 7120;          // [NB] generations (host-zeroed)
  double* Gb = (double*)(ws + O_G);
  __shared__ double Wab_s[2*64*65];
  __shared__ double Vs_s[64*65];
  __shared__ double Rls_s[64*10];
  __shared__ double cc_s[32], ss_s[32], crr_s[64], srr_s[64];
  __shared__ int pp_s[32], qq_s[32], part_s[64], isp_s[64];

  int t = blockIdx.x;
  int g = (t < 160) ? (t/20) : 8;
  int k = (t < 160) ? (t%20) : (t-160);
  int nb16 = desc[48+g];
  int live = 16*nb16;
  int ng = desc[g];
  int ls, nbL;
  if (g < 8) { ls = 16; nbL = nb16; }
  else       { ls = 32; nbL = (nb16 + 1) >> 1; nbL += (nbL & 1); }
  int m = (nbL >= 2) ? nbL - 1 : 1;
  int cap = (g < 8) ? CAPSM : CAP8;
  double* G = Gb + goffd(g);
  double* RBg = (double*)(ws + O_RB) + (size_t)g*1152*9;
  bool bandDone = (nbL < 2);
  int RTg = SWEEPSB*m;

  for (int r = 0; r < RTg; ++r) {
    // band-sweep convergence check (uniform: all band blocks read identical
    // post-barrier sflag state via device-scope RMW) -> whole band exits together
    if (!bandDone && r > 0) {
      int rp = r - 1;
      if ((rp % m) == m-1) {
        int s = rp/m;
        if (atomicOr(&sflag[g*SWEEPSB + s], 0) == 0) bandDone = true;
      }
    }
    if (bandDone) break;
    bool active = (k < nbL/2);
    int cI = 0, cJ = 0;
    if (active) {
      int rr = r % m;
      int I, J;
      if (k == 0) { I = m; J = rr; }
      else { I = (rr + k) % m; J = (rr + m - k) % m; }
      cI = I*ls; cJ = J*ls;
      if (cI >= live && cJ >= live) active = false;
    }
    if (active) {
      int did;
      if (g < 8)
        did = jacobi_visit<32>(G, RBg, cap, ng, live, cI, cJ, Wab_s, Vs_s, Rls_s,
                               cc_s, ss_s, crr_s, srr_s, pp_s, qq_s, part_s, isp_s);
      else
        did = jacobi_visit<64>(G, RBg, cap, ng, live, cI, cJ, Wab_s, Vs_s, Rls_s,
                               cc_s, ss_s, crr_s, srr_s, pp_s, qq_s, part_s, isp_s);
      if (did && threadIdx.x == 0) atomicOr(&sflag[g*SWEEPSB + r/m], 1);
    }
    band_barrier(&barr[g], &bgen[g], 20);
  }
}

// ---------------- eigenvalues: Rayleigh lambda_k = (G_k . HG_k)/(G_k . G_k) ----------------
__global__ void k_eig(char* ws) {
  const int* desc = (const int*)ws;
  double* eva = (double*)(ws + O_EVA);
  int* sid = (int*)(ws + O_SID);
  int wv = (blockIdx.x*blockDim.x + threadIdx.x) >> 6;
  int lane = threadIdx.x & 63;
  if (wv >= SORTN) return;
  if (wv >= NDIM) {
    if (lane == 0) { eva[wv] = 1e300; sid[wv] = wv; }
    return;
  }
  int g = 0;
  while (g < 8 && wv >= desc[16+g+1]) ++g;
  int k = wv - desc[16+g];
  int cap = (g < 8) ? CAPSM : CAP8;
  int ng = desc[g];
  size_t base = goffd(g) + (size_t)k*cap;
  const double* G = (const double*)(ws + O_G) + base;
  const double* HG = (const double*)(ws + O_X1) + base;
  double d1 = 0.0, d2 = 0.0;
  for (int i = lane; i < ng; i += 64) {
    double gv = G[i];
    d1 += gv*HG[i];
    d2 += gv*gv;
  }
  for (int s = 32; s > 0; s >>= 1) {
    d1 += __shfl_xor(d1, s, 64);
    d2 += __shfl_xor(d2, s, 64);
  }
  if (lane == 0) {
    eva[wv] = (d2 > 0.0) ? d1/d2 : 0.0;
    sid[wv] = wv;
  }
}

// ---------------- single-block bitonic sort ----------------
__global__ void k_sort(char* ws) {
  double* key = (double*)(ws + O_EVA);
  int* val = (int*)(ws + O_SID);
  int tid = threadIdx.x;
  for (int size = 2; size <= SORTN; size <<= 1) {
    for (int stride = size >> 1; stride > 0; stride >>= 1) {
      __syncthreads();
      for (int t = tid; t < SORTN/2; t += 1024) {
        int i = 2*t - (t & (stride-1));
        int j = i + stride;
        bool up = ((i & size) == 0);
        double ki = key[i], kj = key[j];
        if ((ki > kj) == up) {
          key[i] = kj; key[j] = ki;
          int v = val[i]; val[i] = val[j]; val[j] = v;
        }
      }
    }
  }
}

// ---------------- final: freq, ir, raman ----------------
__global__ void k_final(char* ws, float* __restrict__ out) {
  int m = blockIdx.x*256 + threadIdx.x;
  if (m >= NOUT) return;
  const int* desc = (const int*)ws;
  const double* eva = (const double*)(ws + O_EVA);
  const int* sid = (const int*)(ws + O_SID);
  int s = m + 6;
  double lam = eva[s];
  int gid = sid[s];
  int g = 0;
  while (g < 8 && gid >= desc[16+g+1]) ++g;
  int k = gid - desc[16+g];
  const double* R = (const double*)(ws + O_RB) + ((size_t)g*1152 + k)*9;
  double q0 = R[0], q1 = R[1], q2 = R[2];
  double ir = 42.2561*(q0*q0 + q1*q1 + q2*q2);
  double xx = R[3], xy = R[4], yy = R[5], xz = R[6], zy = R[7], zz = R[8];
  double alpha = (xx + yy + zz)/3.0;
  double gsq = 0.5*((xx-yy)*(xx-yy) + (yy-zz)*(yy-zz) + (zz-xx)*(zz-xx))
             + 3.0*(xy*xy + xz*xz + zy*zy);
  double raman = (45.0*alpha*alpha + 7.0*gsq)*0.078424;
  double freq = sqrt(fmax(lam, 0.0)*9.375829e28)/(2.0*PI_D)/2.9979245800e10*0.965;
  out[m] = (float)freq;
  out[NOUT + m] = (float)ir;
  out[2*NOUT + m] = (float)raman;
}

__global__ void k_fail(float* out) {
  int i = blockIdx.x*256 + threadIdx.x;
  if (i < 3*NOUT) out[i] = -7777.0f;
}

// ---------------- host ----------------
extern "C" void kernel_launch(void* const* d_in, const int* in_sizes, int n_in,
                              void* d_out, int out_size, void* d_ws, size_t ws_size,
                              hipStream_t stream) {
  const int* z = (const int*)d_in[1];
  const int* ei = (const int*)d_in[2];
  const float* Hi = (const float*)d_in[3];
  const float* Hij = (const float*)d_in[4];
  const float* ded = (const float*)d_in[5];
  const float* dep = (const float*)d_in[6];
  float* out = (float*)d_out;
  char* ws = (char*)d_ws;

  if (ws_size < WS_NEED) {
    k_fail<<<(3*NOUT+255)/256, 256, 0, stream>>>(out);
    return;
  }

  hipMemsetAsync(ws, 0, O_HCOL, stream);
  k_prep<<<1, 256, 0, stream>>>(z, ws);
  k_buildH<<<NA, 128, 0, stream>>>(ei, Hi, Hij, ws);
  k_coeff<<<1, 256, 0, stream>>>(ws);
  k_dt<<<(NDIM+255)/256, 256, 0, stream>>>(ded, dep, ws);

  double* X1 = (double*)(ws + O_X1);    // ortho X, ld=YLD
  double* X2 = (double*)(ws + O_X2);    // cheb output, ld=YLD
  double* Sb = (double*)(ws + O_S);
  double* Pb = (double*)(ws + O_P);
  double* Zb = (double*)(ws + O_S);     // Z chunk aliases S (S dead after NS chain)
  double* Dt = (double*)(ws + O_DT);

  for (int g = 0; g < NB; ++g) {
    int cap = capb(g);
    const int* nbp = ((const int*)(ws)) + 48 + g;
    dim3 gsq((cap+63)/64, (cap+63)/64);
    double* Ag = (double*)(ws + O_G) + goffd(g);   // Ptot ping (dead until Heff)
    double* Bg = (double*)(ws + O_J) + goffd(g);   // Ptot pong (dead until snapshot)

    // ---- column-local Chebyshev -> X2 ----
    k_chebcol<<<dim3((cap+3)/4), 256, 0, stream>>>(ws, g);

    // ---- small-matrix Newton-Schulz on live x live; accumulate Ptot in Ag/Bg ----
    gemm_tn<<<gsq, 256, 0, stream>>>(X2, X2, Sb, cap, cap, NDIM, YLD, YLD, cap, nbp, 1, 1, 0, 0);
    for (int it = 0; it < 5; ++it) {
      gemm_nn<<<gsq, 256, 0, stream>>>(Sb, Sb, Pb, cap, cap, cap, cap, cap, cap, nbp, 1, 1, 0, 1, 1);
      if (it == 0) {
        k_ptinit<<<1024, 256, 0, stream>>>(ws, g, cap);        // Ptot(A) = P1
      } else {
        double* src = (it & 1) ? Ag : Bg;
        double* dst = (it & 1) ? Bg : Ag;
        gemm_nn<<<gsq, 256, 0, stream>>>(src, Pb, dst, cap, cap, cap, cap, cap, cap, nbp, 1, 1, 0, 1, 0);
      }
      if (it < 4) {
        double* Ct = (it & 1) ? Ag : Bg;
        gemm_nn<<<gsq, 256, 0, stream>>>(Sb, Pb, Ct, cap, cap, cap, cap, cap, cap, nbp, 1, 1, 0, 1, 0);
        gemm_nn<<<gsq, 256, 0, stream>>>(Pb, Ct, Sb, cap, cap, cap, cap, cap, cap, nbp, 1, 1, 0, 1, 0);
      }
    }
    // X_ortho = X * Ptot  (Ptot in Ag after it=4)
    gemm_nn<<<dim3((NDIM+63)/64, (cap+63)/64), 256, 0, stream>>>(
        X2, Ag, X1, NDIM, cap, cap, YLD, cap, YLD, nbp, 0, 1, 0, 1, 0);

    // ---- PD_g = X^T Dt ----
    gemm_tn<<<dim3((cap+63)/64, 1), 256, 0, stream>>>(X1, Dt,
        (double*)(ws + O_PD) + (size_t)g*1152*9, cap, 9, NDIM, YLD, 9, 9, nbp, 1, 0, 0, 0);
    // ---- Heff_g = X^T (H X), chunked (overwrites Ag AFTER its last use above) ----
    for (int zc = 0; zc < 2; ++zc) {
      int c0 = zc*ZCHW;
      int cwz = cap - c0; if (cwz > ZCHW) cwz = ZCHW;
      if (cwz <= 0) break;
      dim3 gz(NA, (cwz + 255)/256);
      k_spmm64<<<gz, 256, 0, stream>>>(ws, X1 + c0, Zb, cwz, g, c0, YLD);
      gemm_tn<<<dim3((cap+63)/64, (cwz+63)/64), 256, 0, stream>>>(X1, Zb, Ag + c0,
          cap, cwz, NDIM, YLD, ZCHW, cap, nbp, 1, 1, c0, 0);
    }
    // snapshot Heff -> Jbuf (overwrites Bg scratch), PD -> RB
    k_snap<<<2048, 256, 0, stream>>>(ws, g);
  }

  // joint block one-sided Jacobi on all bands (per-band barriers; bands run concurrently)
  {
    void* args[] = { (void*)&ws };
    hipLaunchCooperativeKernel((void*)k_bjac, dim3(TSLOTS), dim3(256), args, 0, stream);
  }

  // HG_g = G_g(final) x Heff_snapshot  (Rayleigh numerator), per band
  for (int g = 0; g < NB; ++g) {
    int cap = capb(g);
    const int* nbp = ((const int*)(ws)) + 48 + g;
    gemm_nn<<<dim3((cap+63)/64, (cap+63)/64), 256, 0, stream>>>(
        (double*)(ws + O_G) + goffd(g),
        (double*)(ws + O_J) + goffd(g),
        (double*)(ws + O_X1) + goffd(g),
        cap, cap, cap, cap, cap, cap, nbp, 1, 1, 0, 1, 0);
  }

  k_eig<<<(SORTN*64)/256, 256, 0, stream>>>(ws);
  k_sort<<<1, 1024, 0, stream>>>(ws);
  k_final<<<(NOUT+255)/256, 256, 0, stream>>>(ws, out);
}

// Round 14
// 348124.365 us; speedup vs baseline: 1.2165x; 1.0922x over previous
//
#include <hip/hip_runtime.h>
#include <hip/hip_cooperative_groups.h>
#include <math.h>

namespace cg = cooperative_groups;

#define NA      1500
#define NEDGE   48000
#define NDIM    4500
#define NB      9
#define ZCHW    576
#define YLD     1152
#define CAPSM   640
#define CAP8    1152
#define SWEEPSB 8
#define NSWLOC  2
#define TSLOTS  180
#define SORTN   8192
#define COEFLD  864
#define NOUT    4494
#define PI_D    3.14159265358979323846

// Chebyshev filter degrees
static const int H_DEG[NB] = {24, 48, 96, 160, 320, 320, 336, 336, 272};
__device__ __constant__ int d_DEG[NB] = {24, 48, 96, 160, 320, 320, 336, 336, 272};
__device__ __constant__ double d_MASS[10] = {1.008,4.003,6.941,9.012,10.811,12.011,14.007,15.999,18.998,20.18};
__device__ __constant__ double d_BLO[NB] = {31.04695, 9.84715, 6.37590, 5.08655, 4.39385, 3.86620, 3.34740, 2.87855, -1.0e9};
__device__ __constant__ double d_BHI[NB] = {1.0e9, 31.04695, 9.84715, 6.37590, 5.08655, 4.39385, 3.86620, 3.34740, 2.87855};

// ---------------- workspace layout (bytes) ----------------
constexpr size_t O_DESC = 0;
constexpr size_t O_WM   = 32768;
constexpr size_t O_MINV = O_WM + 12288;
constexpr size_t O_GER  = O_MINV + 12288;
constexpr size_t O_CH   = O_GER + 24576;
constexpr size_t O_COEF = O_CH + 256;
constexpr size_t O_DT   = O_COEF + (size_t)NB*COEFLD*8;
constexpr size_t O_PD   = O_DT + (size_t)NDIM*9*8;
constexpr size_t O_RB   = O_PD + (size_t)NB*1152*9*8;
constexpr size_t O_EVA  = O_RB + (size_t)NB*1152*9*8;
constexpr size_t O_SID  = O_EVA + (size_t)SORTN*8;
constexpr size_t O_HCOL = O_SID + (size_t)SORTN*4;
constexpr size_t O_HV64 = O_HCOL + (size_t)NA*65*4;      // f64[1500*65*9] (spmm64)
constexpr size_t O_HV32 = O_HV64 + (size_t)NA*65*9*8;    // (reserved; legacy spacing)
constexpr size_t O_Y    = O_HV32 + (size_t)NA*65*12*4;   // hosts HA/HB/HC f32 transposed H
constexpr size_t O_HA   = O_Y;                           // float4[65*1500]  h[0..3]
constexpr size_t O_HB   = O_HA + (size_t)65*NA*16;       // float4[65*1500]  h[4..7]
constexpr size_t O_HC   = O_HB + (size_t)65*NA*16;       // float [65*1500]  h[8]
constexpr size_t O_X1   = O_Y + (size_t)NDIM*YLD*4;      // ortho X (ld=YLD); HG scratch after bjac
constexpr size_t O_X2   = O_X1 + (size_t)NDIM*YLD*8;     // cheb output (ld=YLD)
constexpr size_t O_S    = O_X2 + (size_t)NDIM*YLD*8;     // S; Z chunk aliases S after NS
constexpr size_t O_P    = O_S + (size_t)CAP8*CAP8*8;     // P
constexpr size_t O_G    = O_P + (size_t)CAP8*CAP8*8;     // Heff; during NS: Ptot ping scratch
constexpr size_t GTOT   = (size_t)8*CAPSM*CAPSM + (size_t)CAP8*CAP8;
constexpr size_t O_J    = O_G + GTOT*8;                  // Heff snapshot; during NS: Ptot pong
constexpr size_t WS_NEED = O_J + GTOT*8;                 // ~213 MB

__host__ __device__ inline size_t goffd(int g){ return (g < 8) ? (size_t)g*CAPSM*CAPSM : (size_t)8*CAPSM*CAPSM; }
__host__ inline int capb(int g){ return (g < 8) ? CAPSM : CAP8; }

// ---------------- prep ----------------
__global__ void k_prep(const int* __restrict__ z, char* ws) {
  int* desc = (int*)ws;
  double* wm = (double*)(ws + O_WM);
  double* minv = (double*)(ws + O_MINV);
  __shared__ int zb[NA];
  __shared__ int cnt[NB];
  int tid = threadIdx.x;
  if (tid < NB) cnt[tid] = 0;
  __syncthreads();
  for (int a = tid; a < NA; a += blockDim.x) {
    int zz = z[a];
    int b = (zz >= 8) ? 8 : zz;
    zb[a] = b;
    atomicAdd(&cnt[b], 1);
    double m = d_MASS[zz];
    wm[a] = 1.0/sqrt(m);
    minv[a] = 1.0/m;
  }
  __syncthreads();
  if (tid == 0) {
    int off = 0;
    for (int g = 0; g < NB; ++g) {
      desc[16+g] = 3*off;
      int ng = 3*cnt[g];
      int cap = (g < 8) ? CAPSM : CAP8;
      ng = (ng > cap) ? cap : ng;
      desc[g] = ng;
      desc[32+g] = ng + (ng & 1);
      int nb = (ng + 15)/16;
      if (nb & 1) nb++;
      desc[48+g] = nb;
      off += cnt[g];
    }
    desc[16+NB] = 3*off;
  }
  __syncthreads();
  for (int a = tid; a < NA; a += blockDim.x) {
    int b = zb[a]; int r = 0;
    for (int x = 0; x < a; ++x) r += (zb[x] == b) ? 1 : 0;
    if (r < 512) desc[64 + b*512 + r] = a;
    desc[5120 + a] = (r & 0xffff) | (b << 16);   // atom -> (rank, band)
  }
}

// ---------------- build sparse mass-weighted symmetrized H ----------------
__global__ void k_buildH(const int* __restrict__ ei, const float* __restrict__ Hi,
                         const float* __restrict__ Hij, char* ws) {
  int p = blockIdx.x, t = threadIdx.x;
  const double* wm = (const double*)(ws + O_WM);
  const double* minv = (const double*)(ws + O_MINV);
  int* hcol = (int*)(ws + O_HCOL);
  double* hv = (double*)(ws + O_HV64);
  float4* HAp = (float4*)(ws + O_HA);
  float4* HBp = (float4*)(ws + O_HB);
  float*  HCp = (float*)(ws + O_HC);
  __shared__ double rowabs[3][72];
  __shared__ double dcen[3];
  double v[9];
  int q = -1;
  if (t == 0) {
    q = p;
    double mi = minv[p];
    for (int a = 0; a < 3; ++a)
      for (int b = 0; b < 3; ++b)
        v[3*a+b] = 0.5*((double)Hi[9*p+3*a+b] + (double)Hi[9*p+3*b+a])*mi;
    for (int a = 0; a < 3; ++a) dcen[a] = v[3*a+a];
  } else if (t <= 32) {
    int off = t;
    int e = 32*p + off - 1;
    q = ei[e];
    double ww = 0.5*wm[p]*wm[q];
    for (int a = 0; a < 3; ++a)
      for (int b = 0; b < 3; ++b)
        v[3*a+b] = ww*(double)Hij[9*e+3*a+b];
  } else if (t <= 64) {
    int off = t - 32;
    int qr = (p + NA - off) % NA;
    int e = 32*qr + off - 1;
    q = ei[NEDGE + e];
    double ww = 0.5*wm[p]*wm[q];
    for (int a = 0; a < 3; ++a)
      for (int b = 0; b < 3; ++b)
        v[3*a+b] = ww*(double)Hij[9*e+3*b+a];
  }
  if (t < 65) {
    hcol[p*65+t] = q;
    for (int k = 0; k < 9; ++k)
      hv[((size_t)p*65+t)*9+k] = v[k];
    HAp[(size_t)t*NA + p] = make_float4((float)v[0],(float)v[1],(float)v[2],(float)v[3]);
    HBp[(size_t)t*NA + p] = make_float4((float)v[4],(float)v[5],(float)v[6],(float)v[7]);
    HCp[(size_t)t*NA + p] = (float)v[8];
    for (int a = 0; a < 3; ++a)
      rowabs[a][t] = fabs(v[3*a]) + fabs(v[3*a+1]) + fabs(v[3*a+2]);
  }
  __syncthreads();
  if (t == 0) {
    double hi = -1e300, lo = 1e300;
    for (int a = 0; a < 3; ++a) {
      double s = 0.0;
      for (int k = 0; k < 65; ++k) s += rowabs[a][k];
      double rad = s - fabs(dcen[a]);
      hi = fmax(hi, dcen[a] + rad);
      lo = fmin(lo, dcen[a] - rad);
    }
    double* ger = (double*)(ws + O_GER);
    ger[2*p] = hi; ger[2*p+1] = lo;
  }
}

// ---------------- spectrum bounds + Jackson-Chebyshev coefficients ----------------
__global__ void k_coeff(char* ws) {
  __shared__ double shi[256], slo[256];
  int tid = threadIdx.x;
  const double* ger = (const double*)(ws + O_GER);
  double hi = -1e300, lo = 1e300;
  for (int i = tid; i < NA; i += 256) { hi = fmax(hi, ger[2*i]); lo = fmin(lo, ger[2*i+1]); }
  shi[tid] = hi; slo[tid] = lo;
  __syncthreads();
  for (int s = 128; s > 0; s >>= 1) {
    if (tid < s) { shi[tid] = fmax(shi[tid], shi[tid+s]); slo[tid] = fmin(slo[tid], slo[tid+s]); }
    __syncthreads();
  }
  double* ch = (double*)(ws + O_CH);
  if (tid == 0) {
    double c = 0.5*(shi[0]+slo[0]);
    double h = 0.5*(shi[0]-slo[0])*1.002;
    ch[0] = c; ch[1] = h;
  }
  __syncthreads();
  double c = ch[0], h = ch[1];
  double* coef = (double*)(ws + O_COEF);
  for (int g = 0; g < NB; ++g) {
    int d = d_DEG[g];
    double xlo = fmin(1.0, fmax(-1.0, (d_BLO[g]-c)/h));
    double xhi = fmin(1.0, fmax(-1.0, (d_BHI[g]-c)/h));
    double f1 = acos(xlo), f2 = acos(xhi);
    double alp = PI_D/(double)(d+1);
    double ct = cos(alp)/sin(alp);
    for (int k = tid; k <= d; k += 256) {
      double ck = (k == 0) ? (f1-f2)/PI_D : 2.0*(sin(k*f1)-sin(k*f2))/(k*PI_D);
      double jk = ((double)(d+1-k)*cos(k*alp) + sin(k*alp)*ct)/(double)(d+1);
      coef[g*COEFLD+k] = ck*jk;
    }
  }
}

// ---------------- mass-weighted dipole/polar matrix Dt[4500][9] ----------------
__global__ void k_dt(const float* __restrict__ ded, const float* __restrict__ dep, char* ws) {
  int row = blockIdx.x*256 + threadIdx.x;
  if (row >= NDIM) return;
  int p = row/3, a = row%3;
  const double* wm = (const double*)(ws + O_WM);
  double w = wm[p];
  double* dt = (double*)(ws + O_DT) + (size_t)row*9;
  for (int cI = 0; cI < 3; ++cI) dt[cI] = w*(double)ded[9*p+3*a+cI];
  for (int cI = 0; cI < 6; ++cI) dt[3+cI] = w*(double)dep[18*p+6*a+cI];
}

// ================= column-local Chebyshev (ZERO per-step boundaries) =================
#define AP(r) ((r) + ((r)>>4))   // LDS pad

__device__ __forceinline__ float4 f4m3(float4 acc, float s0, const float4 v0,
                                       float s1, const float4 v1, float s2, const float4 v2) {
  acc.x += s0*v0.x + s1*v1.x + s2*v2.x;
  acc.y += s0*v0.y + s1*v1.y + s2*v2.y;
  acc.z += s0*v0.z + s1*v1.z + s2*v2.z;
  acc.w += s0*v0.w + s1*v1.w + s2*v2.w;
  return acc;
}

__global__ __launch_bounds__(256, 2) void k_chebcol(char* ws, int g) {
  const int* desc = (const int*)ws;
  const int ng = desc[g];
  const int live = 16*desc[48+g];
  const int c0 = 4*(int)blockIdx.x;
  if (c0 >= live) return;
  const int deg = d_DEG[g];
  const int tid = threadIdx.x;
  __shared__ float4 Asb[AP(4500)];
  const float4* HA = (const float4*)(ws + O_HA);
  const float4* HB = (const float4*)(ws + O_HB);
  const float*  HC = (const float*)(ws + O_HC);
  const double* ch = (const double*)(ws + O_CH);
  const float cc = (float)ch[0];
  const float hinv = (float)(1.0/ch[1]);
  const double* coefd = (const double*)(ws + O_COEF) + (size_t)g*COEFLD;
  const float g0 = (float)coefd[0];

  float4 Bv[18];
  float4 Yv[18];

  #pragma unroll
  for (int i = 0; i < 6; ++i) {
    int atom = tid + 256*i;
    if (atom < NA) {
      int rb = desc[5120 + atom];
      int arank = rb & 0xffff;
      int aband = rb >> 16;
      int jc0 = 3*arank;
      #pragma unroll
      for (int a = 0; a < 3; ++a) {
        float4 t0;
        int jc = jc0 + a;
        bool lv = (aband == g) && (jc < ng);
        t0.x = (lv && jc == c0+0) ? 1.0f : 0.0f;
        t0.y = (lv && jc == c0+1) ? 1.0f : 0.0f;
        t0.z = (lv && jc == c0+2) ? 1.0f : 0.0f;
        t0.w = (lv && jc == c0+3) ? 1.0f : 0.0f;
        Asb[AP(3*atom+a)] = t0;
        Yv[3*i+a] = make_float4(g0*t0.x, g0*t0.y, g0*t0.z, g0*t0.w);
        Bv[3*i+a] = make_float4(0.0f, 0.0f, 0.0f, 0.0f);
      }
    }
  }
  __syncthreads();

  for (int k = 1; k <= deg; ++k) {
    const float gam = (float)coefd[k];
    const bool first = (k == 1);
    #pragma unroll
    for (int i = 0; i < 6; ++i) {
      int atom = tid + 256*i;
      if (atom < NA) {
        float4 acc0 = make_float4(0,0,0,0), acc1 = acc0, acc2 = acc0;
        float4 xd0 = acc0, xd1 = acc0, xd2 = acc0;
        #pragma unroll 5
        for (int du = -32; du <= 32; ++du) {
          int q = atom + du;
          if (q < 0) q += NA; else if (q >= NA) q -= NA;
          int t = (du == 0) ? 0 : ((du > 0) ? du : 32 - du);
          size_t hidx = (size_t)t*NA + atom;
          float4 ha = HA[hidx];
          float4 hb = HB[hidx];
          float  hc = HC[hidx];
          int r = 3*q;
          float4 r0 = Asb[AP(r)];
          float4 r1 = Asb[AP(r+1)];
          float4 r2 = Asb[AP(r+2)];
          if (du == 0) { xd0 = r0; xd1 = r1; xd2 = r2; }
          acc0 = f4m3(acc0, ha.x, r0, ha.y, r1, ha.z, r2);
          acc1 = f4m3(acc1, ha.w, r0, hb.x, r1, hb.y, r2);
          acc2 = f4m3(acc2, hb.z, r0, hb.w, r1, hc,  r2);
        }
        #pragma unroll
        for (int a = 0; a < 3; ++a) {
          float4 accv = (a == 0) ? acc0 : ((a == 1) ? acc1 : acc2);
          float4 xdv  = (a == 0) ? xd0  : ((a == 1) ? xd1  : xd2);
          int bi = 3*i + a;
          float4 u, tn;
          u.x = (accv.x - cc*xdv.x)*hinv;
          u.y = (accv.y - cc*xdv.y)*hinv;
          u.z = (accv.z - cc*xdv.z)*hinv;
          u.w = (accv.w - cc*xdv.w)*hinv;
          tn.x = first ? u.x : (2.0f*u.x - Bv[bi].x);
          tn.y = first ? u.y : (2.0f*u.y - Bv[bi].y);
          tn.z = first ? u.z : (2.0f*u.z - Bv[bi].z);
          tn.w = first ? u.w : (2.0f*u.w - Bv[bi].w);
          Yv[bi].x += gam*tn.x;
          Yv[bi].y += gam*tn.y;
          Yv[bi].z += gam*tn.z;
          Yv[bi].w += gam*tn.w;
          Bv[bi] = tn;
        }
      }
    }
    __syncthreads();
    #pragma unroll
    for (int i = 0; i < 6; ++i) {
      int atom = tid + 256*i;
      if (atom < NA) {
        #pragma unroll
        for (int a = 0; a < 3; ++a) {
          int r = AP(3*atom+a);
          int bi = 3*i + a;
          float4 tmp = Asb[r];
          Asb[r] = Bv[bi];
          Bv[bi] = tmp;
        }
      }
    }
    __syncthreads();
  }

  double* X2 = (double*)(ws + O_X2);
  #pragma unroll
  for (int i = 0; i < 6; ++i) {
    int atom = tid + 256*i;
    if (atom < NA) {
      #pragma unroll
      for (int a = 0; a < 3; ++a) {
        int row = 3*atom + a;
        double* xr = X2 + (size_t)row*YLD;
        float4 y = Yv[3*i+a];
        if (c0+0 < live) xr[c0+0] = (c0+0 < ng) ? (double)y.x : 0.0;
        if (c0+1 < live) xr[c0+1] = (c0+1 < ng) ? (double)y.y : 0.0;
        if (c0+2 < live) xr[c0+2] = (c0+2 < ng) ? (double)y.z : 0.0;
        if (c0+3 < live) xr[c0+3] = (c0+3 < ng) ? (double)y.w : 0.0;
      }
    }
  }
}

// ---------------- f64 SpMM: Z = H * X(cols c0..c0+cw), clamped to live band width ------
__global__ __launch_bounds__(256) void k_spmm64(char* ws, const double* __restrict__ X,
                                                double* __restrict__ Z, int cw, int g, int cpos,
                                                int xld) {
  int live = 16*((const int*)ws)[48+g];
  if (xld < 0) xld = live;
  int cb = blockIdx.y*256;
  if (cpos + cb >= live) return;
  __shared__ double sval[585];
  __shared__ int scol[65];
  int p = blockIdx.x;
  const double* hv = (const double*)(ws + O_HV64) + (size_t)p*585;
  const int* hcol = (const int*)(ws + O_HCOL) + p*65;
  for (int l = threadIdx.x; l < 585; l += 256) sval[l] = hv[l];
  if (threadIdx.x < 65) scol[threadIdx.x] = hcol[threadIdx.x];
  __syncthreads();
  int col = cb + threadIdx.x;
  if (col >= cw || cpos + col >= live) return;
  double a0 = 0.0, a1 = 0.0, a2 = 0.0;
  for (int t = 0; t < 65; ++t) {
    int q = scol[t];
    const double* xb = X + (size_t)(3*q)*xld + col;
    double x0 = xb[0], x1 = xb[xld], x2 = xb[2*xld];
    const double* v = sval + t*9;
    a0 += v[0]*x0 + v[1]*x1 + v[2]*x2;
    a1 += v[3]*x0 + v[4]*x1 + v[5]*x2;
    a2 += v[6]*x0 + v[7]*x1 + v[8]*x2;
  }
  Z[(size_t)(3*p+0)*ZCHW + col] = a0;
  Z[(size_t)(3*p+1)*ZCHW + col] = a1;
  Z[(size_t)(3*p+2)*ZCHW + col] = a2;
}

// ---------------- f64 GEMMs (loads & writes clamped to Ml/Nl/Kl) ----------------
__global__ __launch_bounds__(256) void gemm_tn(const double* __restrict__ A, const double* __restrict__ B,
                                               double* __restrict__ C,
                                               int M, int N, int K, int lda, int ldb, int ldc,
                                               const int* __restrict__ nbp, int cm, int cn, int noff, int ck) {
  int live = nbp ? 16*nbp[0] : 0x7fffffff;
  if (lda < 0) lda = live;
  if (ldb < 0) ldb = live;
  if (ldc < 0) ldc = live;
  int Ml = (cm && live < M) ? live : M;
  int Nl = N;
  if (cn) { int nl = live - noff; Nl = (nl < N) ? nl : N; }
  int Kl = (ck && live < K) ? live : K;
  int i0 = blockIdx.x*64, j0 = blockIdx.y*64;
  if (i0 >= Ml || j0 >= Nl) return;
  __shared__ double As[16][66];
  __shared__ double Bs[16][66];
  int tid = threadIdx.x;
  int tx = tid & 15, ty = tid >> 4;
  double acc[4][4] = {};
  for (int k0 = 0; k0 < Kl; k0 += 16) {
    for (int l = tid; l < 1024; l += 256) {
      int r = l >> 6, c = l & 63;
      int kk = k0 + r;
      As[r][c] = (kk < Kl && i0+c < Ml) ? A[(size_t)kk*lda + i0+c] : 0.0;
    }
    for (int l = tid; l < 1024; l += 256) {
      int r = l >> 6, c = l & 63;
      int kk = k0 + r;
      Bs[r][c] = (kk < Kl && j0+c < Nl) ? B[(size_t)kk*ldb + j0+c] : 0.0;
    }
    __syncthreads();
    for (int kk = 0; kk < 16; ++kk) {
      double a[4], b[4];
      #pragma unroll
      for (int i = 0; i < 4; ++i) { a[i] = As[kk][4*ty+i]; b[i] = Bs[kk][4*tx+i]; }
      #pragma unroll
      for (int i = 0; i < 4; ++i)
        #pragma unroll
        for (int j = 0; j < 4; ++j) acc[i][j] += a[i]*b[j];
    }
    __syncthreads();
  }
  for (int i = 0; i < 4; ++i) {
    int ii = i0 + 4*ty + i;
    if (ii >= Ml) continue;
    for (int j = 0; j < 4; ++j) {
      int jj = j0 + 4*tx + j;
      if (jj < Nl) C[(size_t)ii*ldc + jj] = acc[i][j];
    }
  }
}

// fpb: fused Newton-Schulz P-build epilogue: C = (15*I - 10*A + 3*(A*B))/8  (A==B==S)
__global__ __launch_bounds__(256) void gemm_nn(const double* __restrict__ A, const double* __restrict__ B,
                                               double* __restrict__ C,
                                               int M, int N, int K, int lda, int ldb, int ldc,
                                               const int* __restrict__ nbp, int cm, int cn, int noff, int ck,
                                               int fpb) {
  int live = nbp ? 16*nbp[0] : 0x7fffffff;
  if (lda < 0) lda = live;
  if (ldb < 0) ldb = live;
  if (ldc < 0) ldc = live;
  int Ml = (cm && live < M) ? live : M;
  int Nl = N;
  if (cn) { int nl = live - noff; Nl = (nl < N) ? nl : N; }
  int Kl = (ck && live < K) ? live : K;
  int i0 = blockIdx.x*64, j0 = blockIdx.y*64;
  if (i0 >= Ml || j0 >= Nl) return;
  __shared__ double As[16][66];
  __shared__ double Bs[16][66];
  int tid = threadIdx.x;
  int tx = tid & 15, ty = tid >> 4;
  double acc[4][4] = {};
  for (int k0 = 0; k0 < Kl; k0 += 16) {
    for (int l = tid; l < 1024; l += 256) {
      int r = l & 15, c = l >> 4;
      As[r][c] = ((i0+c) < Ml && (k0+r) < Kl) ? A[(size_t)(i0+c)*lda + k0+r] : 0.0;
    }
    for (int l = tid; l < 1024; l += 256) {
      int r = l >> 6, c = l & 63;
      Bs[r][c] = ((k0+r) < Kl && (j0+c) < Nl) ? B[(size_t)(k0+r)*ldb + j0+c] : 0.0;
    }
    __syncthreads();
    for (int kk = 0; kk < 16; ++kk) {
      double a[4], b[4];
      #pragma unroll
      for (int i = 0; i < 4; ++i) { a[i] = As[kk][4*ty+i]; b[i] = Bs[kk][4*tx+i]; }
      #pragma unroll
      for (int i = 0; i < 4; ++i)
        #pragma unroll
        for (int j = 0; j < 4; ++j) acc[i][j] += a[i]*b[j];
    }
    __syncthreads();
  }
  for (int i = 0; i < 4; ++i) {
    int ii = i0 + 4*ty + i;
    if (ii >= Ml) continue;
    for (int j = 0; j < 4; ++j) {
      int jj = j0 + 4*tx + j;
      if (jj < Nl) {
        if (fpb) {
          double sv = A[(size_t)ii*lda + jj];
          C[(size_t)ii*ldc + jj] = (15.0*((ii==jj) ? 1.0 : 0.0) - 10.0*sv + 3.0*acc[i][j])*0.125;
        } else {
          C[(size_t)ii*ldc + jj] = acc[i][j];
        }
      }
    }
  }
}

// ---------------- Ptot init: copy live x live of P (ld=cap) into G_g scratch (ld=cap) ------
__global__ void k_ptinit(char* ws, int g, int cap) {
  int live = 16*((const int*)ws)[48+g];
  const double* P = (const double*)(ws + O_P);
  double* A = (double*)(ws + O_G) + goffd(g);
  size_t n = (size_t)live*live;
  for (size_t i = (size_t)blockIdx.x*256 + threadIdx.x; i < n; i += (size_t)gridDim.x*256) {
    int r = (int)(i / live), c = (int)(i % live);
    A[(size_t)r*cap + c] = P[(size_t)r*cap + c];
  }
}

// ---------------- per-band snapshot: Heff copy (G->Jbuf) + RB init (PD->RB) ----------------
__global__ void k_snap(char* ws, int g) {
  const int* desc = (const int*)ws;
  int live = 16*desc[48+g];
  int cap = (g < 8) ? CAPSM : CAP8;
  size_t n1 = (size_t)cap*live;
  size_t n2 = (size_t)live*9;
  const double* Gsrc = (const double*)(ws + O_G) + goffd(g);
  double* Jdst = (double*)(ws + O_J) + goffd(g);
  const double* PD = (const double*)(ws + O_PD) + (size_t)g*1152*9;
  double* RB = (double*)(ws + O_RB) + (size_t)g*1152*9;
  for (size_t i = (size_t)blockIdx.x*256 + threadIdx.x; i < n1 + n2; i += (size_t)gridDim.x*256) {
    if (i < n1) Jdst[i] = Gsrc[i];
    else RB[i - n1] = PD[i - n1];
  }
}

// ---------------- block one-sided Jacobi (R6-exact visit; PER-BAND barriers) ----------------
// NSWLOC=2 (block-Jacobi needs only partial local convergence per visit) and rotation
// threshold 1e-10 (skip |w_pq| < 1e-5*scale; eigvec perturbation O(1e-5)). Convergence
// safety net unchanged: SWEEPSB global sweeps + per-sweep rotation flags + early exits.
template<int L>
__device__ __forceinline__ int jacobi_visit(double* __restrict__ G, double* __restrict__ RBg,
    int cap, int ng, int live, int cI, int cJ,
    double* Wab, double* Vs, double* Rls,
    double* cc_, double* ss_, double* crr_, double* srr_,
    int* pp_, int* qq_, int* part_, int* isp_) {
  constexpr int ls = L/2;
  constexpr int P2 = L/2;
  constexpr int ldw = L + 1;
  constexpr int WSZ = 64*65;
  constexpr int AB = L/16;
  const int tid = threadIdx.x;
  const int tx = tid & 15, ty = tid >> 4;
  // ---- gram: W = [G_I|G_J]^T [G_I|G_J]  (Vs aliased as row-chunk staging) ----
  double w[AB][AB];
  #pragma unroll
  for (int a = 0; a < AB; ++a)
    #pragma unroll
    for (int b = 0; b < AB; ++b) w[a][b] = 0.0;
  for (int i0 = 0; i0 < ng; i0 += 64) {
    for (int e = tid; e < 64*L; e += 256) {
      int rw = e & 63, j = e >> 6;
      int cidx = (j < ls) ? (cI + j) : (cJ + (j - ls));
      int i = i0 + rw;
      Vs[rw*ldw + j] = (i < ng && cidx < live) ? G[(size_t)cidx*cap + i] : 0.0;
    }
    __syncthreads();
    #pragma unroll 4
    for (int rw = 0; rw < 64; ++rw) {
      double ra[AB], rb[AB];
      #pragma unroll
      for (int a = 0; a < AB; ++a) ra[a] = Vs[rw*ldw + ty + 16*a];
      #pragma unroll
      for (int b = 0; b < AB; ++b) rb[b] = Vs[rw*ldw + tx + 16*b];
      #pragma unroll
      for (int a = 0; a < AB; ++a)
        #pragma unroll
        for (int b = 0; b < AB; ++b) w[a][b] += ra[a]*rb[b];
    }
    __syncthreads();
  }
  #pragma unroll
  for (int a = 0; a < AB; ++a)
    #pragma unroll
    for (int b = 0; b < AB; ++b)
      Wab[(ty + 16*a)*ldw + tx + 16*b] = w[a][b];
  for (int e = tid; e < L*L; e += 256) {
    int r = e / L, c = e % L;
    Vs[r*ldw + c] = (r == c) ? 1.0 : 0.0;
  }
  __syncthreads();
  // ---- local two-sided Jacobi on W ----
  int cur = 0;
  int blockAny = 0;
  for (int sw = 0; sw < NSWLOC; ++sw) {
    int sweepAny = 0;
    for (int rr2 = 0; rr2 < L-1; ++rr2) {
      int myrot = 0;
      if (tid < P2) {
        int pid = tid, p2, q2;
        if (pid == 0) { p2 = L-1; q2 = rr2; }
        else { p2 = (rr2 + pid) % (L-1); q2 = (rr2 + (L-1) - pid) % (L-1); }
        const double* Wc = Wab + cur*WSZ;
        double wpp = Wc[p2*ldw+p2], wqq = Wc[q2*ldw+q2], wpq = Wc[p2*ldw+q2];
        bool rot = (wpq*wpq > 1e-10*fabs(wpp*wqq) + 1e-280);
        double cr = 1.0, sr = 0.0;
        if (rot) {
          double tau = (wqq - wpp)/(2.0*wpq);
          double tt = (tau >= 0.0 ? 1.0 : -1.0)/(fabs(tau) + sqrt(1.0 + tau*tau));
          cr = 1.0/sqrt(1.0 + tt*tt);
          sr = tt*cr;
        }
        pp_[pid] = p2; qq_[pid] = q2; cc_[pid] = cr; ss_[pid] = sr;
        part_[p2] = q2; part_[q2] = p2;
        isp_[p2] = 1;  isp_[q2] = 0;
        crr_[p2] = cr; crr_[q2] = cr;
        srr_[p2] = sr; srr_[q2] = sr;
        myrot = rot ? 1 : 0;
      }
      int any = __syncthreads_or(myrot);
      if (any) {
        sweepAny = 1;
        const double* Wc = Wab + cur*WSZ;
        double* Wn = Wab + (cur^1)*WSZ;
        #pragma unroll
        for (int jj = 0; jj < (L*P2)/256; ++jj) {
          int e = tid + 256*jj;
          int rw = e / P2, pid = e % P2;
          int p = pp_[pid], q = qq_[pid];
          double cr = cc_[pid], sr = ss_[pid];
          int prn = part_[rw];
          double crR = crr_[rw], srR = srr_[rw];
          int rowIsP = isp_[rw];
          double wrp = Wc[rw*ldw+p],  wrq = Wc[rw*ldw+q];
          double wop = Wc[prn*ldw+p], woq = Wc[prn*ldw+q];
          double rvp, rvq;
          if (rowIsP) { rvp = crR*wrp - srR*wop; rvq = crR*wrq - srR*woq; }
          else        { rvp = srR*wop + crR*wrp; rvq = srR*woq + crR*wrq; }
          Wn[rw*ldw+p] = cr*rvp - sr*rvq;
          Wn[rw*ldw+q] = sr*rvp + cr*rvq;
          double vp = Vs[rw*ldw+p], vq = Vs[rw*ldw+q];
          Vs[rw*ldw+p] = cr*vp - sr*vq;
          Vs[rw*ldw+q] = sr*vp + cr*vq;
        }
        __syncthreads();
        cur ^= 1;
      }
    }
    blockAny |= sweepAny;
    if (!sweepAny) break;
  }
  if (!blockAny) return 0;   // V == I exactly: R and panels unchanged
  // ---- R update: R_panel <- V^T R_panel ----
  for (int e = tid; e < L*9; e += 256) {
    int s = e/9, c = e - 9*s;
    int cidx = (s < ls) ? (cI + s) : (cJ + (s - ls));
    Rls[s*10 + c] = (cidx < live) ? RBg[(size_t)cidx*9 + c] : 0.0;
  }
  __syncthreads();
  for (int e = tid; e < L*9; e += 256) {
    int r = e/9, c = e - 9*r;
    int cidx = (r < ls) ? (cI + r) : (cJ + (r - ls));
    if (cidx < live) {
      double s = 0.0;
      #pragma unroll
      for (int s2 = 0; s2 < L; ++s2) s += Vs[s2*ldw + r]*Rls[s2*10 + c];
      RBg[(size_t)cidx*9 + c] = s;
    }
  }
  // ---- panel update: [G_I|G_J] <- [G_I|G_J] * V ----
  for (int i = tid; i < ng; i += 256) {
    double bg[L];
    #pragma unroll
    for (int rw = 0; rw < L; ++rw) {
      int cidx = (rw < ls) ? (cI + rw) : (cJ + (rw - ls));
      bg[rw] = (cidx < live) ? G[(size_t)cidx*cap + i] : 0.0;
    }
    for (int p = 0; p < L; ++p) {
      double s = 0.0;
      #pragma unroll
      for (int rw = 0; rw < L; ++rw) s += bg[rw]*Vs[rw*ldw + p];
      int cidx = (p < ls) ? (cI + p) : (cJ + (p - ls));
      if (cidx < live) G[(size_t)cidx*cap + i] = s;
    }
  }
  return 1;
}

// per-band sense-reversing barrier (device-scope atomics; blocks co-resident via coop launch)
__device__ __forceinline__ void band_barrier(int* arr, int* gen, int nblk) {
  __syncthreads();
  if (threadIdx.x == 0) {
    __threadfence();   // release: panel/flag writes visible before arrival
    int my = __hip_atomic_load(gen, __ATOMIC_RELAXED, __HIP_MEMORY_SCOPE_AGENT);
    int cnt = __hip_atomic_fetch_add(arr, 1, __ATOMIC_ACQ_REL, __HIP_MEMORY_SCOPE_AGENT);
    if (cnt == nblk - 1) {
      __hip_atomic_store(arr, 0, __ATOMIC_RELAXED, __HIP_MEMORY_SCOPE_AGENT);
      __hip_atomic_fetch_add(gen, 1, __ATOMIC_ACQ_REL, __HIP_MEMORY_SCOPE_AGENT);
    } else {
      while (__hip_atomic_load(gen, __ATOMIC_ACQUIRE, __HIP_MEMORY_SCOPE_AGENT) == my)
        __builtin_amdgcn_s_sleep(2);
    }
    __threadfence();   // acquire: other blocks' writes visible after release
  }
  __syncthreads();
}

__global__ __launch_bounds__(256) void k_bjac(char* ws) {
  const int* desc = (const int*)ws;
  int* sflag = (int*)ws + 7000;          // [NB][SWEEPSB] rotation flags (host-zeroed)
  int* barr  = (int*)ws + 7100;          // [NB] arrival counters (host-zeroed)
  int* bgen  = (int*)ws + 7120;          // [NB] generations (host-zeroed)
  double* Gb = (double*)(ws + O_G);
  __shared__ double Wab_s[2*64*65];
  __shared__ double Vs_s[64*65];
  __shared__ double Rls_s[64*10];
  __shared__ double cc_s[32], ss_s[32], crr_s[64], srr_s[64];
  __shared__ int pp_s[32], qq_s[32], part_s[64], isp_s[64];

  int t = blockIdx.x;
  int g = (t < 160) ? (t/20) : 8;
  int k = (t < 160) ? (t%20) : (t-160);
  int nb16 = desc[48+g];
  int live = 16*nb16;
  int ng = desc[g];
  int ls, nbL;
  if (g < 8) { ls = 16; nbL = nb16; }
  else       { ls = 32; nbL = (nb16 + 1) >> 1; nbL += (nbL & 1); }
  int m = (nbL >= 2) ? nbL - 1 : 1;
  int cap = (g < 8) ? CAPSM : CAP8;
  double* G = Gb + goffd(g);
  double* RBg = (double*)(ws + O_RB) + (size_t)g*1152*9;
  bool bandDone = (nbL < 2);
  int RTg = SWEEPSB*m;

  for (int r = 0; r < RTg; ++r) {
    // band-sweep convergence check (uniform: all band blocks read identical
    // post-barrier sflag state via device-scope RMW) -> whole band exits together
    if (!bandDone && r > 0) {
      int rp = r - 1;
      if ((rp % m) == m-1) {
        int s = rp/m;
        if (atomicOr(&sflag[g*SWEEPSB + s], 0) == 0) bandDone = true;
      }
    }
    if (bandDone) break;
    bool active = (k < nbL/2);
    int cI = 0, cJ = 0;
    if (active) {
      int rr = r % m;
      int I, J;
      if (k == 0) { I = m; J = rr; }
      else { I = (rr + k) % m; J = (rr + m - k) % m; }
      cI = I*ls; cJ = J*ls;
      if (cI >= live && cJ >= live) active = false;
    }
    if (active) {
      int did;
      if (g < 8)
        did = jacobi_visit<32>(G, RBg, cap, ng, live, cI, cJ, Wab_s, Vs_s, Rls_s,
                               cc_s, ss_s, crr_s, srr_s, pp_s, qq_s, part_s, isp_s);
      else
        did = jacobi_visit<64>(G, RBg, cap, ng, live, cI, cJ, Wab_s, Vs_s, Rls_s,
                               cc_s, ss_s, crr_s, srr_s, pp_s, qq_s, part_s, isp_s);
      if (did && threadIdx.x == 0) atomicOr(&sflag[g*SWEEPSB + r/m], 1);
    }
    band_barrier(&barr[g], &bgen[g], 20);
  }
}

// ---------------- eigenvalues: Rayleigh lambda_k = (G_k . HG_k)/(G_k . G_k) ----------------
__global__ void k_eig(char* ws) {
  const int* desc = (const int*)ws;
  double* eva = (double*)(ws + O_EVA);
  int* sid = (int*)(ws + O_SID);
  int wv = (blockIdx.x*blockDim.x + threadIdx.x) >> 6;
  int lane = threadIdx.x & 63;
  if (wv >= SORTN) return;
  if (wv >= NDIM) {
    if (lane == 0) { eva[wv] = 1e300; sid[wv] = wv; }
    return;
  }
  int g = 0;
  while (g < 8 && wv >= desc[16+g+1]) ++g;
  int k = wv - desc[16+g];
  int cap = (g < 8) ? CAPSM : CAP8;
  int ng = desc[g];
  size_t base = goffd(g) + (size_t)k*cap;
  const double* G = (const double*)(ws + O_G) + base;
  const double* HG = (const double*)(ws + O_X1) + base;
  double d1 = 0.0, d2 = 0.0;
  for (int i = lane; i < ng; i += 64) {
    double gv = G[i];
    d1 += gv*HG[i];
    d2 += gv*gv;
  }
  for (int s = 32; s > 0; s >>= 1) {
    d1 += __shfl_xor(d1, s, 64);
    d2 += __shfl_xor(d2, s, 64);
  }
  if (lane == 0) {
    eva[wv] = (d2 > 0.0) ? d1/d2 : 0.0;
    sid[wv] = wv;
  }
}

// ---------------- single-block bitonic sort ----------------
__global__ void k_sort(char* ws) {
  double* key = (double*)(ws + O_EVA);
  int* val = (int*)(ws + O_SID);
  int tid = threadIdx.x;
  for (int size = 2; size <= SORTN; size <<= 1) {
    for (int stride = size >> 1; stride > 0; stride >>= 1) {
      __syncthreads();
      for (int t = tid; t < SORTN/2; t += 1024) {
        int i = 2*t - (t & (stride-1));
        int j = i + stride;
        bool up = ((i & size) == 0);
        double ki = key[i], kj = key[j];
        if ((ki > kj) == up) {
          key[i] = kj; key[j] = ki;
          int v = val[i]; val[i] = val[j]; val[j] = v;
        }
      }
    }
  }
}

// ---------------- final: freq, ir, raman ----------------
__global__ void k_final(char* ws, float* __restrict__ out) {
  int m = blockIdx.x*256 + threadIdx.x;
  if (m >= NOUT) return;
  const int* desc = (const int*)ws;
  const double* eva = (const double*)(ws + O_EVA);
  const int* sid = (const int*)(ws + O_SID);
  int s = m + 6;
  double lam = eva[s];
  int gid = sid[s];
  int g = 0;
  while (g < 8 && gid >= desc[16+g+1]) ++g;
  int k = gid - desc[16+g];
  const double* R = (const double*)(ws + O_RB) + ((size_t)g*1152 + k)*9;
  double q0 = R[0], q1 = R[1], q2 = R[2];
  double ir = 42.2561*(q0*q0 + q1*q1 + q2*q2);
  double xx = R[3], xy = R[4], yy = R[5], xz = R[6], zy = R[7], zz = R[8];
  double alpha = (xx + yy + zz)/3.0;
  double gsq = 0.5*((xx-yy)*(xx-yy) + (yy-zz)*(yy-zz) + (zz-xx)*(zz-xx))
             + 3.0*(xy*xy + xz*xz + zy*zy);
  double raman = (45.0*alpha*alpha + 7.0*gsq)*0.078424;
  double freq = sqrt(fmax(lam, 0.0)*9.375829e28)/(2.0*PI_D)/2.9979245800e10*0.965;
  out[m] = (float)freq;
  out[NOUT + m] = (float)ir;
  out[2*NOUT + m] = (float)raman;
}

__global__ void k_fail(float* out) {
  int i = blockIdx.x*256 + threadIdx.x;
  if (i < 3*NOUT) out[i] = -7777.0f;
}

// ---------------- host ----------------
extern "C" void kernel_launch(void* const* d_in, const int* in_sizes, int n_in,
                              void* d_out, int out_size, void* d_ws, size_t ws_size,
                              hipStream_t stream) {
  const int* z = (const int*)d_in[1];
  const int* ei = (const int*)d_in[2];
  const float* Hi = (const float*)d_in[3];
  const float* Hij = (const float*)d_in[4];
  const float* ded = (const float*)d_in[5];
  const float* dep = (const float*)d_in[6];
  float* out = (float*)d_out;
  char* ws = (char*)d_ws;

  if (ws_size < WS_NEED) {
    k_fail<<<(3*NOUT+255)/256, 256, 0, stream>>>(out);
    return;
  }

  hipMemsetAsync(ws, 0, O_HCOL, stream);
  k_prep<<<1, 256, 0, stream>>>(z, ws);
  k_buildH<<<NA, 128, 0, stream>>>(ei, Hi, Hij, ws);
  k_coeff<<<1, 256, 0, stream>>>(ws);
  k_dt<<<(NDIM+255)/256, 256, 0, stream>>>(ded, dep, ws);

  double* X1 = (double*)(ws + O_X1);    // ortho X, ld=YLD
  double* X2 = (double*)(ws + O_X2);    // cheb output, ld=YLD
  double* Sb = (double*)(ws + O_S);
  double* Pb = (double*)(ws + O_P);
  double* Zb = (double*)(ws + O_S);     // Z chunk aliases S (S dead after NS chain)
  double* Dt = (double*)(ws + O_DT);

  for (int g = 0; g < NB; ++g) {
    int cap = capb(g);
    const int* nbp = ((const int*)(ws)) + 48 + g;
    dim3 gsq((cap+63)/64, (cap+63)/64);
    double* Ag = (double*)(ws + O_G) + goffd(g);   // Ptot ping (dead until Heff)
    double* Bg = (double*)(ws + O_J) + goffd(g);   // Ptot pong (dead until snapshot)

    // ---- column-local Chebyshev -> X2 ----
    k_chebcol<<<dim3((cap+3)/4), 256, 0, stream>>>(ws, g);

    // ---- small-matrix Newton-Schulz on live x live; accumulate Ptot in Ag/Bg ----
    gemm_tn<<<gsq, 256, 0, stream>>>(X2, X2, Sb, cap, cap, NDIM, YLD, YLD, cap, nbp, 1, 1, 0, 0);
    for (int it = 0; it < 5; ++it) {
      gemm_nn<<<gsq, 256, 0, stream>>>(Sb, Sb, Pb, cap, cap, cap, cap, cap, cap, nbp, 1, 1, 0, 1, 1);
      if (it == 0) {
        k_ptinit<<<1024, 256, 0, stream>>>(ws, g, cap);        // Ptot(A) = P1
      } else {
        double* src = (it & 1) ? Ag : Bg;
        double* dst = (it & 1) ? Bg : Ag;
        gemm_nn<<<gsq, 256, 0, stream>>>(src, Pb, dst, cap, cap, cap, cap, cap, cap, nbp, 1, 1, 0, 1, 0);
      }
      if (it < 4) {
        double* Ct = (it & 1) ? Ag : Bg;
        gemm_nn<<<gsq, 256, 0, stream>>>(Sb, Pb, Ct, cap, cap, cap, cap, cap, cap, nbp, 1, 1, 0, 1, 0);
        gemm_nn<<<gsq, 256, 0, stream>>>(Pb, Ct, Sb, cap, cap, cap, cap, cap, cap, nbp, 1, 1, 0, 1, 0);
      }
    }
    // X_ortho = X * Ptot  (Ptot in Ag after it=4)
    gemm_nn<<<dim3((NDIM+63)/64, (cap+63)/64), 256, 0, stream>>>(
        X2, Ag, X1, NDIM, cap, cap, YLD, cap, YLD, nbp, 0, 1, 0, 1, 0);

    // ---- PD_g = X^T Dt ----
    gemm_tn<<<dim3((cap+63)/64, 1), 256, 0, stream>>>(X1, Dt,
        (double*)(ws + O_PD) + (size_t)g*1152*9, cap, 9, NDIM, YLD, 9, 9, nbp, 1, 0, 0, 0);
    // ---- Heff_g = X^T (H X), chunked (overwrites Ag AFTER its last use above) ----
    for (int zc = 0; zc < 2; ++zc) {
      int c0 = zc*ZCHW;
      int cwz = cap - c0; if (cwz > ZCHW) cwz = ZCHW;
      if (cwz <= 0) break;
      dim3 gz(NA, (cwz + 255)/256);
      k_spmm64<<<gz, 256, 0, stream>>>(ws, X1 + c0, Zb, cwz, g, c0, YLD);
      gemm_tn<<<dim3((cap+63)/64, (cwz+63)/64), 256, 0, stream>>>(X1, Zb, Ag + c0,
          cap, cwz, NDIM, YLD, ZCHW, cap, nbp, 1, 1, c0, 0);
    }
    // snapshot Heff -> Jbuf (overwrites Bg scratch), PD -> RB
    k_snap<<<2048, 256, 0, stream>>>(ws, g);
  }

  // joint block one-sided Jacobi on all bands (per-band barriers; bands run concurrently)
  {
    void* args[] = { (void*)&ws };
    hipLaunchCooperativeKernel((void*)k_bjac, dim3(TSLOTS), dim3(256), args, 0, stream);
  }

  // HG_g = G_g(final) x Heff_snapshot  (Rayleigh numerator), per band
  for (int g = 0; g < NB; ++g) {
    int cap = capb(g);
    const int* nbp = ((const int*)(ws)) + 48 + g;
    gemm_nn<<<dim3((cap+63)/64, (cap+63)/64), 256, 0, stream>>>(
        (double*)(ws + O_G) + goffd(g),
        (double*)(ws + O_J) + goffd(g),
        (double*)(ws + O_X1) + goffd(g),
        cap, cap, cap, cap, cap, cap, nbp, 1, 1, 0, 1, 0);
  }

  k_eig<<<(SORTN*64)/256, 256, 0, stream>>>(ws);
  k_sort<<<1, 1024, 0, stream>>>(ws);
  k_final<<<(NOUT+255)/256, 256, 0, stream>>>(ws, out);
}